// Round 7
// baseline (121.313 us; speedup 1.0000x reference)
//
#include <hip/hip_runtime.h>

#define TEMP 10.0f
#define NS 4096
#define BB 512
#define DDIM 512
#define NCLS 10
#define LDSP 72

typedef short bf16x8 __attribute__((ext_vector_type(8)));
typedef float f32x4 __attribute__((ext_vector_type(4)));

__device__ inline short f2bf(float f) {
    unsigned u = __builtin_bit_cast(unsigned, f);
    u += 0x7FFFu + ((u >> 16) & 1u);      // round-to-nearest-even
    return (short)(u >> 16);
}
__device__ inline float bf2f(short h) {
    unsigned u = ((unsigned)(unsigned short)h) << 16;
    return __builtin_bit_cast(float, u);
}

// =============== block-wide sum helper ===============
__device__ inline float block_sum(float s, float* red) {
    #pragma unroll
    for (int off = 32; off > 0; off >>= 1) s += __shfl_down(s, off);
    int wid = threadIdx.x >> 6;
    if ((threadIdx.x & 63) == 0) red[wid] = s;
    __syncthreads();
    float tot = red[0] + red[1] + red[2] + red[3];
    __syncthreads();
    return tot;
}

// =============== column means + total square-sums of star / from ===============
// blocks 0..15: star cols [bid*32,+32) -> sbar, sssp[bid]
// blocks 16..31: from likewise -> fbar, fssp[bid-16]
__global__ __launch_bounds__(256)
void colmeans(const float* __restrict__ star, const float* __restrict__ from,
              float* __restrict__ sbar, float* __restrict__ fbar,
              float* __restrict__ sssp, float* __restrict__ fssp)
{
    __shared__ float csl[8][33];
    __shared__ float red[4];
    int bid = blockIdx.x, t = threadIdx.x;
    const float* M; float* outm; float* outss; int ib;
    if (bid < 16) { M = star; outm = sbar; outss = sssp; ib = bid; }
    else          { M = from; outm = fbar; outss = fssp; ib = bid - 16; }
    int d0 = ib * 32, rg = t >> 5, dc = t & 31;
    float cs = 0.f, sq = 0.f;
    #pragma unroll 4
    for (int r = rg; r < NS; r += 8) {
        float v = M[(size_t)r * DDIM + d0 + dc];
        cs += v; sq += v * v;
    }
    csl[rg][dc] = cs;
    float sqt = block_sum(sq, red);   // includes barrier -> csl visible after
    if (t == 0) outss[ib] = sqt;
    if (t < 32) {
        float s = 0.f;
        #pragma unroll
        for (int q = 0; q < 8; ++q) s += csl[q][t];
        outm[d0 + t] = s * (1.0f / NS);
    }
}

// =============== prep: conversions / norms / col0 extraction ===============
__global__ __launch_bounds__(256)
void prep(const float* __restrict__ x, const float* __restrict__ star,
          const float* __restrict__ from,
          short* __restrict__ Xb, short* __restrict__ Sb,
          short* __restrict__ FTb, short* __restrict__ Fb,
          float* __restrict__ xn2, float* __restrict__ sn2, float* __restrict__ fn2,
          float* __restrict__ scol, float* __restrict__ xcol, int* __restrict__ midx)
{
    int bid = blockIdx.x, t = threadIdx.x;
    if (bid < 2176) {
        const float* in; short* outb; float* n2; float* colb; int rowbase;
        if (bid < 1024)      { in = star; outb = Sb; n2 = sn2; colb = scol; rowbase = bid * 4; }
        else if (bid < 1152) { in = x;    outb = Xb; n2 = xn2; colb = xcol; rowbase = (bid - 1024) * 4; }
        else                 { in = from; outb = Fb; n2 = fn2; colb = nullptr; rowbase = (bid - 1152) * 4; }
        if (bid == 1024) { midx[t] = NS; midx[256 + t] = NS; }
        int row = rowbase + (t >> 6);
        int l = t & 63;
        const float4* p = (const float4*)(in + (size_t)row * DDIM) + l * 2;
        float4 a = p[0], b = p[1];
        float s = a.x*a.x + a.y*a.y + a.z*a.z + a.w*a.w
                + b.x*b.x + b.y*b.y + b.z*b.z + b.w*b.w;
        bf16x8 h;
        h[0]=f2bf(a.x); h[1]=f2bf(a.y); h[2]=f2bf(a.z); h[3]=f2bf(a.w);
        h[4]=f2bf(b.x); h[5]=f2bf(b.y); h[6]=f2bf(b.z); h[7]=f2bf(b.w);
        *(bf16x8*)(outb + (size_t)row * DDIM + l * 8) = h;
        #pragma unroll
        for (int off = 32; off > 0; off >>= 1) s += __shfl_down(s, off);
        if (l == 0) {
            n2[row] = s;
            if (colb) colb[row] = a.x;
        }
        return;
    }
    // ---- from transpose tile ----
    __shared__ short tile[64][LDSP];
    int tid2 = bid - 2176;
    int n0 = (tid2 & 63) * 64, d0 = (tid2 >> 6) * 64;
    int r = t >> 4, c4 = (t & 15) * 4;
    #pragma unroll
    for (int rr = 0; rr < 64; rr += 16) {
        float4 v = *(const float4*)(from + (size_t)(n0 + r + rr) * DDIM + d0 + c4);
        tile[r + rr][c4 + 0] = f2bf(v.x);
        tile[r + rr][c4 + 1] = f2bf(v.y);
        tile[r + rr][c4 + 2] = f2bf(v.z);
        tile[r + rr][c4 + 3] = f2bf(v.w);
    }
    __syncthreads();
    int dr = t >> 2, nco = (t & 3) * 16;
    short tmp[16];
    #pragma unroll
    for (int q = 0; q < 16; ++q) tmp[q] = tile[nco + q][dr];
    short* op = FTb + (size_t)(d0 + dr) * NS + n0 + nco;
    *(bf16x8*)op       = *(bf16x8*)tmp;
    *(bf16x8*)(op + 8) = *(bf16x8*)(tmp + 8);
}

// =============== escale1[b] = -T / (mean(sn2) + xn2[b] - 2*sbar.x_b) ===============
__global__ __launch_bounds__(256)
void scale1(const float* __restrict__ x, const float* __restrict__ sbar,
            const float* __restrict__ sssp, const float* __restrict__ xn2,
            float* __restrict__ escale1)
{
    int t = threadIdx.x;
    int lane = t & 63, w = t >> 6;
    int b = blockIdx.x * 4 + w;
    const float4* xp = (const float4*)(x + (size_t)b * DDIM) + lane * 2;
    const float4* sp = (const float4*)sbar + lane * 2;
    float4 xa = xp[0], xb = xp[1], sa = sp[0], sb = sp[1];
    float dot = xa.x*sa.x + xa.y*sa.y + xa.z*sa.z + xa.w*sa.w
              + xb.x*sb.x + xb.y*sb.y + xb.z*sb.z + xb.w*sb.w;
    float ss = (lane < 16) ? sssp[lane] : 0.f;
    #pragma unroll
    for (int m = 32; m > 0; m >>= 1) {
        dot += __shfl_xor(dot, m);
        ss  += __shfl_xor(ss, m);
    }
    if (lane == 0)
        escale1[b] = -TEMP / (ss * (1.0f / NS) + xn2[b] - 2.0f * dot);
}

// =============== exact-match scan: 16 blocks, one thread per star row ===============
__global__ __launch_bounds__(256)
void match16(const float* __restrict__ x, const float* __restrict__ star,
             const float* __restrict__ scol, const float* __restrict__ xcol,
             int* __restrict__ midx)
{
    __shared__ float xl[BB];
    int t = threadIdx.x;
    *(float2*)&xl[t * 2] = *(const float2*)&xcol[t * 2];
    __syncthreads();
    int n = blockIdx.x * 256 + t;
    float sv = scol[n];
    #pragma unroll 4
    for (int b4 = 0; b4 < BB; b4 += 4) {
        float4 xv = *(const float4*)&xl[b4];
        if (xv.x == sv || xv.y == sv || xv.z == sv || xv.w == sv) {
            #pragma unroll
            for (int j = 0; j < 4; ++j) {
                int b = b4 + j;
                if (xl[b] == sv) {
                    const float* xr = x + (size_t)b * DDIM;
                    const float* sr = star + (size_t)n * DDIM;
                    bool eq = true;
                    for (int k = 0; k < DDIM && eq; k += 4) {
                        float4 a = *(const float4*)(xr + k);
                        float4 c = *(const float4*)(sr + k);
                        eq = (a.x == c.x) && (a.y == c.y) &&
                             (a.z == c.z) && (a.w == c.w);
                    }
                    if (eq) atomicMin(&midx[b], n);
                }
            }
        }
    }
}

// ====== MFMA GEMM + fused sqdist/exp epilogue -> bf16 E, optional sumE partials ======
// E[m][n] = bf16(exp(escale[m] * max(an2[m]+bn2[n]-2*dot(A[m],B[n]), 0)))
// WSE: sumEp[m][32] gets this block's n-tile partial sum (deterministic, no atomics).
template<int WSE>
__global__ __launch_bounds__(256)
void gemm_exp(const short* __restrict__ A, const short* __restrict__ B,
              const float* __restrict__ an2, const float* __restrict__ bn2,
              const float* __restrict__ escale, short* __restrict__ Eout,
              float* __restrict__ sumEp)
{
    __shared__ short As[2][64][LDSP];
    __shared__ short Bs[2][128][LDSP];
    __shared__ float se[2][64];
    const int K = DDIM;
    int t = threadIdx.x;
    int m0 = blockIdx.x * 64;
    int n0 = blockIdx.y * 128;
    int wid = t >> 6, lane = t & 63;
    int wr = wid >> 1, wc = wid & 1;
    int lr = lane & 15, lk = lane >> 4;

    int ar = t >> 2, ak = (t & 3) * 16;
    int br = t >> 1, bk = (t & 1) * 32;
    const short* Ag = A + (size_t)(m0 + ar) * K + ak;
    const short* Bg = B + (size_t)(n0 + br) * K + bk;

    f32x4 acc[2][4] = {};
    bf16x8 ra0 = *(const bf16x8*)Ag;
    bf16x8 ra1 = *(const bf16x8*)(Ag + 8);
    bf16x8 rb0 = *(const bf16x8*)Bg;
    bf16x8 rb1 = *(const bf16x8*)(Bg + 8);
    bf16x8 rb2 = *(const bf16x8*)(Bg + 16);
    bf16x8 rb3 = *(const bf16x8*)(Bg + 24);
    int cur = 0;
    *(bf16x8*)&As[0][ar][ak]      = ra0;
    *(bf16x8*)&As[0][ar][ak + 8]  = ra1;
    *(bf16x8*)&Bs[0][br][bk]      = rb0;
    *(bf16x8*)&Bs[0][br][bk + 8]  = rb1;
    *(bf16x8*)&Bs[0][br][bk + 16] = rb2;
    *(bf16x8*)&Bs[0][br][bk + 24] = rb3;

    const int nt = K / 64;
    for (int it = 0; it < nt; ++it) {
        __syncthreads();
        if (it + 1 < nt) {
            int ko = (it + 1) * 64;
            ra0 = *(const bf16x8*)(Ag + ko);
            ra1 = *(const bf16x8*)(Ag + ko + 8);
            rb0 = *(const bf16x8*)(Bg + ko);
            rb1 = *(const bf16x8*)(Bg + ko + 8);
            rb2 = *(const bf16x8*)(Bg + ko + 16);
            rb3 = *(const bf16x8*)(Bg + ko + 24);
        }
        #pragma unroll
        for (int ks = 0; ks < 2; ++ks) {
            int k0 = ks * 32 + lk * 8;
            bf16x8 af[2], bfr[4];
            #pragma unroll
            for (int i = 0; i < 2; ++i)
                af[i] = *(const bf16x8*)&As[cur][wr * 32 + i * 16 + lr][k0];
            #pragma unroll
            for (int j = 0; j < 4; ++j)
                bfr[j] = *(const bf16x8*)&Bs[cur][wc * 64 + j * 16 + lr][k0];
            #pragma unroll
            for (int i = 0; i < 2; ++i)
                #pragma unroll
                for (int j = 0; j < 4; ++j)
                    acc[i][j] = __builtin_amdgcn_mfma_f32_16x16x32_bf16(
                        af[i], bfr[j], acc[i][j], 0, 0, 0);
        }
        if (it + 1 < nt) {
            cur ^= 1;
            *(bf16x8*)&As[cur][ar][ak]      = ra0;
            *(bf16x8*)&As[cur][ar][ak + 8]  = ra1;
            *(bf16x8*)&Bs[cur][br][bk]      = rb0;
            *(bf16x8*)&Bs[cur][br][bk + 8]  = rb1;
            *(bf16x8*)&Bs[cur][br][bk + 16] = rb2;
            *(bf16x8*)&Bs[cur][br][bk + 24] = rb3;
        }
    }
    // ---- epilogue: clamp + exp + bf16 store (+ per-block sumE partials) ----
    float bn2v[4];
    int gnv[4];
    #pragma unroll
    for (int j = 0; j < 4; ++j) { gnv[j] = n0 + wc * 64 + j * 16 + lr; bn2v[j] = bn2[gnv[j]]; }
    #pragma unroll
    for (int i = 0; i < 2; ++i) {
        #pragma unroll
        for (int r = 0; r < 4; ++r) {
            int gm = m0 + wr * 32 + i * 16 + lk * 4 + r;
            float a2 = an2[gm];
            float sc = escale[gm];
            float rs = 0.f;
            #pragma unroll
            for (int j = 0; j < 4; ++j) {
                float dv = fmaxf(a2 + bn2v[j] - 2.0f * acc[i][j][r], 0.0f);
                short hb = f2bf(__expf(dv * sc));
                Eout[(size_t)gm * NS + gnv[j]] = hb;
                if (WSE) rs += bf2f(hb);
            }
            if (WSE) {
                #pragma unroll
                for (int m = 1; m < 16; m <<= 1) rs += __shfl_xor(rs, m);
                if (lr == 0) se[wc][wr * 32 + i * 16 + lk * 4 + r] = rs;
            }
        }
    }
    if (WSE) {
        __syncthreads();
        if (t < 64) sumEp[(size_t)(m0 + t) * 32 + blockIdx.y] = se[0][t] + se[1][t];
    }
}

// =============== MFMA GEMM raw partials (for w = e @ fromT, K-split) ===============
__global__ __launch_bounds__(256)
void gemm_bt(const short* __restrict__ A, const short* __restrict__ B, int K,
             int kslab, int nt, float* __restrict__ C, int ldc, size_t cstride)
{
    __shared__ short As[2][64][LDSP];
    __shared__ short Bs[2][128][LDSP];
    int t = threadIdx.x;
    int m0 = blockIdx.x * 64;
    int n0 = blockIdx.y * 128;
    int kbase = blockIdx.z * kslab;
    float* Cp = C + (size_t)blockIdx.z * cstride;
    int wid = t >> 6, lane = t & 63;
    int wr = wid >> 1, wc = wid & 1;
    int lr = lane & 15, lk = lane >> 4;

    int ar = t >> 2, ak = (t & 3) * 16;
    int br = t >> 1, bk = (t & 1) * 32;
    const short* Ag = A + (size_t)(m0 + ar) * K + kbase + ak;
    const short* Bg = B + (size_t)(n0 + br) * K + kbase + bk;

    f32x4 acc[2][4] = {};
    bf16x8 ra0 = *(const bf16x8*)Ag;
    bf16x8 ra1 = *(const bf16x8*)(Ag + 8);
    bf16x8 rb0 = *(const bf16x8*)Bg;
    bf16x8 rb1 = *(const bf16x8*)(Bg + 8);
    bf16x8 rb2 = *(const bf16x8*)(Bg + 16);
    bf16x8 rb3 = *(const bf16x8*)(Bg + 24);
    int cur = 0;
    *(bf16x8*)&As[0][ar][ak]      = ra0;
    *(bf16x8*)&As[0][ar][ak + 8]  = ra1;
    *(bf16x8*)&Bs[0][br][bk]      = rb0;
    *(bf16x8*)&Bs[0][br][bk + 8]  = rb1;
    *(bf16x8*)&Bs[0][br][bk + 16] = rb2;
    *(bf16x8*)&Bs[0][br][bk + 24] = rb3;

    for (int it = 0; it < nt; ++it) {
        __syncthreads();
        if (it + 1 < nt) {
            int ko = (it + 1) * 64;
            ra0 = *(const bf16x8*)(Ag + ko);
            ra1 = *(const bf16x8*)(Ag + ko + 8);
            rb0 = *(const bf16x8*)(Bg + ko);
            rb1 = *(const bf16x8*)(Bg + ko + 8);
            rb2 = *(const bf16x8*)(Bg + ko + 16);
            rb3 = *(const bf16x8*)(Bg + ko + 24);
        }
        #pragma unroll
        for (int ks = 0; ks < 2; ++ks) {
            int k0 = ks * 32 + lk * 8;
            bf16x8 af[2], bfr[4];
            #pragma unroll
            for (int i = 0; i < 2; ++i)
                af[i] = *(const bf16x8*)&As[cur][wr * 32 + i * 16 + lr][k0];
            #pragma unroll
            for (int j = 0; j < 4; ++j)
                bfr[j] = *(const bf16x8*)&Bs[cur][wc * 64 + j * 16 + lr][k0];
            #pragma unroll
            for (int i = 0; i < 2; ++i)
                #pragma unroll
                for (int j = 0; j < 4; ++j)
                    acc[i][j] = __builtin_amdgcn_mfma_f32_16x16x32_bf16(
                        af[i], bfr[j], acc[i][j], 0, 0, 0);
        }
        if (it + 1 < nt) {
            cur ^= 1;
            *(bf16x8*)&As[cur][ar][ak]      = ra0;
            *(bf16x8*)&As[cur][ar][ak + 8]  = ra1;
            *(bf16x8*)&Bs[cur][br][bk]      = rb0;
            *(bf16x8*)&Bs[cur][br][bk + 8]  = rb1;
            *(bf16x8*)&Bs[cur][br][bk + 16] = rb2;
            *(bf16x8*)&Bs[cur][br][bk + 24] = rb3;
        }
    }
    #pragma unroll
    for (int i = 0; i < 2; ++i) {
        #pragma unroll
        for (int r = 0; r < 4; ++r) {
            int gm = m0 + wr * 32 + i * 16 + lk * 4 + r;
            #pragma unroll
            for (int j = 0; j < 4; ++j) {
                int gn = n0 + wc * 64 + j * 16 + lr;
                Cp[(size_t)gm * ldc + gn] = acc[i][j][r];
            }
        }
    }
}

// === xt = (sum of 16 w-slabs)/sumE (or matched row) -> bf16 + norm + escale2 ===
__global__ __launch_bounds__(256)
void xt_fin(const float* __restrict__ wpart, const float* __restrict__ sumEp,
            const int* __restrict__ midx, const float* __restrict__ fromf,
            const float* __restrict__ fbar, const float* __restrict__ fssp,
            short* __restrict__ xtb, float* __restrict__ xtn2,
            float* __restrict__ escale2)
{
    __shared__ float red[4];
    __shared__ float bc[2];
    int b = blockIdx.x;
    int t = threadIdx.x;
    int d = t * 2;
    int mi = midx[b];
    if (t == 0) {
        float s = 0.f;
        #pragma unroll
        for (int k = 0; k < 32; ++k) s += sumEp[(size_t)b * 32 + k];
        float f = 0.f;
        #pragma unroll
        for (int k = 0; k < 16; ++k) f += fssp[k];
        bc[0] = 1.0f / s;
        bc[1] = f * (1.0f / NS);
    }
    float v0 = 0.f, v1 = 0.f;
    #pragma unroll
    for (int sl = 0; sl < 16; ++sl) {
        float2 p = *(const float2*)(wpart + (size_t)sl * (BB * DDIM) + (size_t)b * DDIM + d);
        v0 += p.x; v1 += p.y;
    }
    __syncthreads();
    float inv = bc[0], fmean = bc[1];
    v0 *= inv; v1 *= inv;
    if (mi < NS) {
        v0 = fromf[(size_t)mi * DDIM + d];
        v1 = fromf[(size_t)mi * DDIM + d + 1];
    }
    xtb[(size_t)b * DDIM + d]     = f2bf(v0);
    xtb[(size_t)b * DDIM + d + 1] = f2bf(v1);
    float nt2 = block_sum(v0 * v0 + v1 * v1, red);
    float2 fb2 = *(const float2*)(fbar + d);
    float fd = block_sum(v0 * fb2.x + v1 * fb2.y, red);
    if (t == 0) {
        xtn2[b] = nt2;
        escale2[b] = -TEMP / (fmean + nt2 - 2.0f * fd);
    }
}

// =============== y_star from bf16 e2T: weighted one-hot average ===============
__global__ __launch_bounds__(256)
void ystar_fin(const short* __restrict__ e2T, const int* __restrict__ labels,
               float* __restrict__ out)
{
    __shared__ float cred[NCLS + 1][4];
    int b = blockIdx.x;
    int t = threadIdx.x;
    const short* row = e2T + (size_t)b * NS + t * 16;
    bf16x8 h0 = *(const bf16x8*)row;
    bf16x8 h1 = *(const bf16x8*)(row + 8);
    float accs[NCLS] = {};
    float te = 0.f;
    #pragma unroll
    for (int q = 0; q < 4; ++q) {
        int4 lb = *(const int4*)(labels + t * 16 + q * 4);
        int lbl[4] = {lb.x, lb.y, lb.z, lb.w};
        #pragma unroll
        for (int e = 0; e < 4; ++e) {
            int idx = q * 4 + e;
            float ev = bf2f(idx < 8 ? h0[idx] : h1[idx - 8]);
            te += ev;
            #pragma unroll
            for (int c = 0; c < NCLS; ++c) accs[c] += (lbl[e] == c) ? ev : 0.f;
        }
    }
    int wid = t >> 6, lane = t & 63;
    #pragma unroll
    for (int c = 0; c < NCLS + 1; ++c) {
        float sv = (c < NCLS) ? accs[c] : te;
        #pragma unroll
        for (int off = 32; off > 0; off >>= 1) sv += __shfl_down(sv, off);
        if (lane == 0) cred[c][wid] = sv;
    }
    __syncthreads();
    if (t < NCLS) {
        float num = cred[t][0] + cred[t][1] + cred[t][2] + cred[t][3];
        float den = cred[NCLS][0] + cred[NCLS][1] + cred[NCLS][2] + cred[NCLS][3];
        out[b * NCLS + t] = num / den;
    }
}

extern "C" void kernel_launch(void* const* d_in, const int* in_sizes, int n_in,
                              void* d_out, int out_size, void* d_ws, size_t ws_size,
                              hipStream_t stream) {
    const float* x     = (const float*)d_in[0];
    const float* star  = (const float*)d_in[1];
    const float* from  = (const float*)d_in[2];
    const int*   label = (const int*)d_in[3];
    float* out = (float*)d_out;

    float* F = (float*)d_ws;                     // ~39 MB of 256 MiB workspace
    float* wpart = F;                            // 16 x [512][512] f32 (16 MB)
    short* Sb    = (short*)(F + 4194304);        // star bf16  [4096][512]
    short* FTb   = (short*)(F + 5242880);        // fromT bf16 [512][4096]
    short* Fb    = (short*)(F + 6291456);        // from bf16  [4096][512]
    short* Eb    = (short*)(F + 7340032);        // eT bf16    [512][4096]
    short* E2b   = (short*)(F + 8388608);        // e2T bf16   [512][4096]
    short* Xb    = (short*)(F + 9437184);        // x bf16     [512][512]
    short* XTb   = (short*)(F + 9568256);        // xt bf16    [512][512]
    float* sn2   = F + 9699328;                  // 4096
    float* fn2   = F + 9703424;                  // 4096
    float* xn2   = F + 9707520;                  // 512
    float* xtn2  = F + 9708032;                  // 512
    float* esc1  = F + 9708544;                  // 512
    float* esc2  = F + 9709056;                  // 512
    float* sbar  = F + 9709568;                  // 512
    float* fbar  = F + 9710080;                  // 512
    float* sssp  = F + 9710592;                  // 16
    float* fssp  = F + 9710608;                  // 16
    float* sumEp = F + 9710624;                  // [512][32]
    float* scol  = F + 9727008;                  // 4096
    float* xcol  = F + 9731104;                  // 512
    int*   midx  = (int*)(F + 9731616);          // 512

    colmeans<<<32, 256, 0, stream>>>(star, from, sbar, fbar, sssp, fssp);
    prep<<<2688, 256, 0, stream>>>(x, star, from, Xb, Sb, FTb, Fb,
                                   xn2, sn2, fn2, scol, xcol, midx);
    scale1<<<128, 256, 0, stream>>>(x, sbar, sssp, xn2, esc1);
    match16<<<16, 256, 0, stream>>>(x, star, scol, xcol, midx);
    // eT[b][n] = bf16(exp(esc1[b]*clamp(xn2+sn2-2 x.star,0))) + sumE partials
    gemm_exp<1><<<dim3(8, 32), 256, 0, stream>>>(Xb, Sb, xn2, sn2, esc1, Eb, sumEp);
    // wpart[z][b][d] = sum_{n in slab z} eT[b][n]*fromT[d][n]
    gemm_bt<<<dim3(8, 4, 16), 256, 0, stream>>>(Eb, FTb, NS, 256, 4, wpart, DDIM,
                                                (size_t)BB * DDIM);
    xt_fin<<<BB, 256, 0, stream>>>(wpart, sumEp, midx, from, fbar, fssp,
                                   XTb, xtn2, esc2);
    // e2T[b][n] = bf16(exp(esc2[b]*clamp(xtn2+fn2-2 xt.from,0)))
    gemm_exp<0><<<dim3(8, 32), 256, 0, stream>>>(XTb, Fb, xtn2, fn2, esc2, E2b, nullptr);
    ystar_fin<<<BB, 256, 0, stream>>>(E2b, label, out);
}

// Round 8
// 84.842 us; speedup vs baseline: 1.4299x; 1.4299x over previous
//
#include <hip/hip_runtime.h>

#define TEMP 10.0f
#define NS 4096
#define BB 512
#define DDIM 512
#define NCLS 10
#define LDSP 72

typedef short bf16x8 __attribute__((ext_vector_type(8)));
typedef float f32x4 __attribute__((ext_vector_type(4)));

__device__ inline short f2bf(float f) {
    unsigned u = __builtin_bit_cast(unsigned, f);
    u += 0x7FFFu + ((u >> 16) & 1u);      // round-to-nearest-even
    return (short)(u >> 16);
}
__device__ inline float bf2f(short h) {
    unsigned u = ((unsigned)(unsigned short)h) << 16;
    return __builtin_bit_cast(float, u);
}

// =============== block-wide sum helper ===============
__device__ inline float block_sum(float s, float* red) {
    #pragma unroll
    for (int off = 32; off > 0; off >>= 1) s += __shfl_down(s, off);
    int wid = threadIdx.x >> 6;
    if ((threadIdx.x & 63) == 0) red[wid] = s;
    __syncthreads();
    float tot = red[0] + red[1] + red[2] + red[3];
    __syncthreads();
    return tot;
}

// =============== prep: conversions / norms / col0 / colsum partials ===============
// blocks [0,1024)    : star rows -> Sb bf16 + sn2 + scol
// blocks [1024,1152) : x rows    -> Xb bf16 + xn2 + xcol (+ midx init on block 1024)
// blocks [1152,2176) : from rows -> Fb bf16 + fn2
// blocks [2176,2688) : from tiles -> FTb (bf16 transpose [DDIM][NS])
// blocks [2688,2944) : 32-row colsum partials (128 star -> spart, 128 from -> fpart)
__global__ __launch_bounds__(256)
void prep(const float* __restrict__ x, const float* __restrict__ star,
          const float* __restrict__ from,
          short* __restrict__ Xb, short* __restrict__ Sb,
          short* __restrict__ FTb, short* __restrict__ Fb,
          float* __restrict__ xn2, float* __restrict__ sn2, float* __restrict__ fn2,
          float* __restrict__ scol, float* __restrict__ xcol, int* __restrict__ midx,
          float* __restrict__ spart, float* __restrict__ fpart)
{
    int bid = blockIdx.x, t = threadIdx.x;
    if (bid < 2176) {
        const float* in; short* outb; float* n2; float* colb; int rowbase;
        if (bid < 1024)      { in = star; outb = Sb; n2 = sn2; colb = scol; rowbase = bid * 4; }
        else if (bid < 1152) { in = x;    outb = Xb; n2 = xn2; colb = xcol; rowbase = (bid - 1024) * 4; }
        else                 { in = from; outb = Fb; n2 = fn2; colb = nullptr; rowbase = (bid - 1152) * 4; }
        if (bid == 1024) { midx[t] = NS; midx[256 + t] = NS; }
        int row = rowbase + (t >> 6);
        int l = t & 63;
        const float4* p = (const float4*)(in + (size_t)row * DDIM) + l * 2;
        float4 a = p[0], b = p[1];
        float s = a.x*a.x + a.y*a.y + a.z*a.z + a.w*a.w
                + b.x*b.x + b.y*b.y + b.z*b.z + b.w*b.w;
        bf16x8 h;
        h[0]=f2bf(a.x); h[1]=f2bf(a.y); h[2]=f2bf(a.z); h[3]=f2bf(a.w);
        h[4]=f2bf(b.x); h[5]=f2bf(b.y); h[6]=f2bf(b.z); h[7]=f2bf(b.w);
        *(bf16x8*)(outb + (size_t)row * DDIM + l * 8) = h;
        #pragma unroll
        for (int off = 32; off > 0; off >>= 1) s += __shfl_down(s, off);
        if (l == 0) {
            n2[row] = s;
            if (colb) colb[row] = a.x;
        }
        return;
    }
    if (bid >= 2688) {
        // ---- coalesced 32-row column-sum partial ----
        __shared__ float cp[512];
        int ib = bid - 2688;                  // 0..255
        const float* M = (ib < 128) ? star : from;
        float* part = (ib < 128) ? spart : fpart;
        int r0 = (ib & 127) * 32;
        int c4 = (t & 127) * 4, rg = t >> 7;
        float4 acc = {0.f, 0.f, 0.f, 0.f};
        #pragma unroll 4
        for (int r = rg; r < 32; r += 2) {
            float4 v = *(const float4*)(M + (size_t)(r0 + r) * DDIM + c4);
            acc.x += v.x; acc.y += v.y; acc.z += v.z; acc.w += v.w;
        }
        if (rg == 1) *(float4*)&cp[c4] = acc;
        __syncthreads();
        if (rg == 0) {
            float4 o = *(const float4*)&cp[c4];
            acc.x += o.x; acc.y += o.y; acc.z += o.z; acc.w += o.w;
            *(float4*)&part[(size_t)(ib & 127) * 512 + c4] = acc;
        }
        return;
    }
    // ---- from transpose tile ----
    __shared__ short tile[64][LDSP];
    int tid2 = bid - 2176;
    int n0 = (tid2 & 63) * 64, d0 = (tid2 >> 6) * 64;
    int r = t >> 4, c4 = (t & 15) * 4;
    #pragma unroll
    for (int rr = 0; rr < 64; rr += 16) {
        float4 v = *(const float4*)(from + (size_t)(n0 + r + rr) * DDIM + d0 + c4);
        tile[r + rr][c4 + 0] = f2bf(v.x);
        tile[r + rr][c4 + 1] = f2bf(v.y);
        tile[r + rr][c4 + 2] = f2bf(v.z);
        tile[r + rr][c4 + 3] = f2bf(v.w);
    }
    __syncthreads();
    int dr = t >> 2, nco = (t & 3) * 16;
    short tmp[16];
    #pragma unroll
    for (int q = 0; q < 16; ++q) tmp[q] = tile[nco + q][dr];
    short* op = FTb + (size_t)(d0 + dr) * NS + n0 + nco;
    *(bf16x8*)op       = *(bf16x8*)tmp;
    *(bf16x8*)(op + 8) = *(bf16x8*)(tmp + 8);
}

// ===== finmeans: 2 blocks. Reduce colsum partials -> sbar/fbar; mean(n2) -> sms/fms =====
__global__ __launch_bounds__(256)
void finmeans(const float* __restrict__ spart, const float* __restrict__ fpart,
              const float* __restrict__ sn2, const float* __restrict__ fn2,
              float* __restrict__ sbar, float* __restrict__ fbar,
              float* __restrict__ sms, float* __restrict__ fms)
{
    __shared__ float red[4];
    int bid = blockIdx.x, t = threadIdx.x;
    const float* part = bid ? fpart : spart;
    const float* n2v  = bid ? fn2 : sn2;
    float* outm = bid ? fbar : sbar;
    float* outs = bid ? fms : sms;
    float ax = 0.f, ay = 0.f;
    #pragma unroll 8
    for (int k = 0; k < 128; ++k) {
        float2 v = *(const float2*)(part + (size_t)k * 512 + t * 2);
        ax += v.x; ay += v.y;
    }
    float2 o; o.x = ax * (1.0f / NS); o.y = ay * (1.0f / NS);
    *(float2*)(outm + t * 2) = o;
    float s = 0.f;
    #pragma unroll
    for (int q = 0; q < 16; ++q) s += n2v[q * 256 + t];
    float tot = block_sum(s, red);
    if (t == 0) outs[0] = tot * (1.0f / NS);
}

// =============== escale1[b] = -T / (sms + xn2[b] - 2*sbar.x_b) ===============
__global__ __launch_bounds__(256)
void scale1(const float* __restrict__ x, const float* __restrict__ sbar,
            const float* __restrict__ sms, const float* __restrict__ xn2,
            float* __restrict__ escale1)
{
    int t = threadIdx.x;
    int lane = t & 63, w = t >> 6;
    int b = blockIdx.x * 4 + w;
    const float4* xp = (const float4*)(x + (size_t)b * DDIM) + lane * 2;
    const float4* sp = (const float4*)sbar + lane * 2;
    float4 xa = xp[0], xb = xp[1], sa = sp[0], sb = sp[1];
    float dot = xa.x*sa.x + xa.y*sa.y + xa.z*sa.z + xa.w*sa.w
              + xb.x*sb.x + xb.y*sb.y + xb.z*sb.z + xb.w*sb.w;
    #pragma unroll
    for (int m = 32; m > 0; m >>= 1) dot += __shfl_xor(dot, m);
    if (lane == 0)
        escale1[b] = -TEMP / (sms[0] + xn2[b] - 2.0f * dot);
}

// =============== exact-match scan: 16 blocks, one thread per star row ===============
__global__ __launch_bounds__(256)
void match16(const float* __restrict__ x, const float* __restrict__ star,
             const float* __restrict__ scol, const float* __restrict__ xcol,
             int* __restrict__ midx)
{
    __shared__ float xl[BB];
    int t = threadIdx.x;
    *(float2*)&xl[t * 2] = *(const float2*)&xcol[t * 2];
    __syncthreads();
    int n = blockIdx.x * 256 + t;
    float sv = scol[n];
    #pragma unroll 4
    for (int b4 = 0; b4 < BB; b4 += 4) {
        float4 xv = *(const float4*)&xl[b4];
        if (xv.x == sv || xv.y == sv || xv.z == sv || xv.w == sv) {
            #pragma unroll
            for (int j = 0; j < 4; ++j) {
                int b = b4 + j;
                if (xl[b] == sv) {
                    const float* xr = x + (size_t)b * DDIM;
                    const float* sr = star + (size_t)n * DDIM;
                    bool eq = true;
                    for (int k = 0; k < DDIM && eq; k += 4) {
                        float4 a = *(const float4*)(xr + k);
                        float4 c = *(const float4*)(sr + k);
                        eq = (a.x == c.x) && (a.y == c.y) &&
                             (a.z == c.z) && (a.w == c.w);
                    }
                    if (eq) atomicMin(&midx[b], n);
                }
            }
        }
    }
}

// ====== MFMA GEMM + fused sqdist/exp epilogue -> bf16 E, optional sumE partials ======
template<int WSE>
__global__ __launch_bounds__(256)
void gemm_exp(const short* __restrict__ A, const short* __restrict__ B,
              const float* __restrict__ an2, const float* __restrict__ bn2,
              const float* __restrict__ escale, short* __restrict__ Eout,
              float* __restrict__ sumEp)
{
    __shared__ short As[2][64][LDSP];
    __shared__ short Bs[2][128][LDSP];
    __shared__ float se[2][64];
    const int K = DDIM;
    int t = threadIdx.x;
    int m0 = blockIdx.x * 64;
    int n0 = blockIdx.y * 128;
    int wid = t >> 6, lane = t & 63;
    int wr = wid >> 1, wc = wid & 1;
    int lr = lane & 15, lk = lane >> 4;

    int ar = t >> 2, ak = (t & 3) * 16;
    int br = t >> 1, bk = (t & 1) * 32;
    const short* Ag = A + (size_t)(m0 + ar) * K + ak;
    const short* Bg = B + (size_t)(n0 + br) * K + bk;

    f32x4 acc[2][4] = {};
    bf16x8 ra0 = *(const bf16x8*)Ag;
    bf16x8 ra1 = *(const bf16x8*)(Ag + 8);
    bf16x8 rb0 = *(const bf16x8*)Bg;
    bf16x8 rb1 = *(const bf16x8*)(Bg + 8);
    bf16x8 rb2 = *(const bf16x8*)(Bg + 16);
    bf16x8 rb3 = *(const bf16x8*)(Bg + 24);
    int cur = 0;
    *(bf16x8*)&As[0][ar][ak]      = ra0;
    *(bf16x8*)&As[0][ar][ak + 8]  = ra1;
    *(bf16x8*)&Bs[0][br][bk]      = rb0;
    *(bf16x8*)&Bs[0][br][bk + 8]  = rb1;
    *(bf16x8*)&Bs[0][br][bk + 16] = rb2;
    *(bf16x8*)&Bs[0][br][bk + 24] = rb3;

    const int nt = K / 64;
    for (int it = 0; it < nt; ++it) {
        __syncthreads();
        if (it + 1 < nt) {
            int ko = (it + 1) * 64;
            ra0 = *(const bf16x8*)(Ag + ko);
            ra1 = *(const bf16x8*)(Ag + ko + 8);
            rb0 = *(const bf16x8*)(Bg + ko);
            rb1 = *(const bf16x8*)(Bg + ko + 8);
            rb2 = *(const bf16x8*)(Bg + ko + 16);
            rb3 = *(const bf16x8*)(Bg + ko + 24);
        }
        #pragma unroll
        for (int ks = 0; ks < 2; ++ks) {
            int k0 = ks * 32 + lk * 8;
            bf16x8 af[2], bfr[4];
            #pragma unroll
            for (int i = 0; i < 2; ++i)
                af[i] = *(const bf16x8*)&As[cur][wr * 32 + i * 16 + lr][k0];
            #pragma unroll
            for (int j = 0; j < 4; ++j)
                bfr[j] = *(const bf16x8*)&Bs[cur][wc * 64 + j * 16 + lr][k0];
            #pragma unroll
            for (int i = 0; i < 2; ++i)
                #pragma unroll
                for (int j = 0; j < 4; ++j)
                    acc[i][j] = __builtin_amdgcn_mfma_f32_16x16x32_bf16(
                        af[i], bfr[j], acc[i][j], 0, 0, 0);
        }
        if (it + 1 < nt) {
            cur ^= 1;
            *(bf16x8*)&As[cur][ar][ak]      = ra0;
            *(bf16x8*)&As[cur][ar][ak + 8]  = ra1;
            *(bf16x8*)&Bs[cur][br][bk]      = rb0;
            *(bf16x8*)&Bs[cur][br][bk + 8]  = rb1;
            *(bf16x8*)&Bs[cur][br][bk + 16] = rb2;
            *(bf16x8*)&Bs[cur][br][bk + 24] = rb3;
        }
    }
    // ---- epilogue: clamp + exp + bf16 store (+ per-block sumE partials) ----
    float bn2v[4];
    int gnv[4];
    #pragma unroll
    for (int j = 0; j < 4; ++j) { gnv[j] = n0 + wc * 64 + j * 16 + lr; bn2v[j] = bn2[gnv[j]]; }
    #pragma unroll
    for (int i = 0; i < 2; ++i) {
        #pragma unroll
        for (int r = 0; r < 4; ++r) {
            int gm = m0 + wr * 32 + i * 16 + lk * 4 + r;
            float a2 = an2[gm];
            float sc = escale[gm];
            float rs = 0.f;
            #pragma unroll
            for (int j = 0; j < 4; ++j) {
                float dv = fmaxf(a2 + bn2v[j] - 2.0f * acc[i][j][r], 0.0f);
                short hb = f2bf(__expf(dv * sc));
                Eout[(size_t)gm * NS + gnv[j]] = hb;
                if (WSE) rs += bf2f(hb);
            }
            if (WSE) {
                #pragma unroll
                for (int m = 1; m < 16; m <<= 1) rs += __shfl_xor(rs, m);
                if (lr == 0) se[wc][wr * 32 + i * 16 + lk * 4 + r] = rs;
            }
        }
    }
    if (WSE) {
        __syncthreads();
        if (t < 64) sumEp[(size_t)(m0 + t) * 32 + blockIdx.y] = se[0][t] + se[1][t];
    }
}

// =============== MFMA GEMM raw partials (for w = e @ fromT, K-split) ===============
__global__ __launch_bounds__(256)
void gemm_bt(const short* __restrict__ A, const short* __restrict__ B, int K,
             int kslab, int nt, float* __restrict__ C, int ldc, size_t cstride)
{
    __shared__ short As[2][64][LDSP];
    __shared__ short Bs[2][128][LDSP];
    int t = threadIdx.x;
    int m0 = blockIdx.x * 64;
    int n0 = blockIdx.y * 128;
    int kbase = blockIdx.z * kslab;
    float* Cp = C + (size_t)blockIdx.z * cstride;
    int wid = t >> 6, lane = t & 63;
    int wr = wid >> 1, wc = wid & 1;
    int lr = lane & 15, lk = lane >> 4;

    int ar = t >> 2, ak = (t & 3) * 16;
    int br = t >> 1, bk = (t & 1) * 32;
    const short* Ag = A + (size_t)(m0 + ar) * K + kbase + ak;
    const short* Bg = B + (size_t)(n0 + br) * K + kbase + bk;

    f32x4 acc[2][4] = {};
    bf16x8 ra0 = *(const bf16x8*)Ag;
    bf16x8 ra1 = *(const bf16x8*)(Ag + 8);
    bf16x8 rb0 = *(const bf16x8*)Bg;
    bf16x8 rb1 = *(const bf16x8*)(Bg + 8);
    bf16x8 rb2 = *(const bf16x8*)(Bg + 16);
    bf16x8 rb3 = *(const bf16x8*)(Bg + 24);
    int cur = 0;
    *(bf16x8*)&As[0][ar][ak]      = ra0;
    *(bf16x8*)&As[0][ar][ak + 8]  = ra1;
    *(bf16x8*)&Bs[0][br][bk]      = rb0;
    *(bf16x8*)&Bs[0][br][bk + 8]  = rb1;
    *(bf16x8*)&Bs[0][br][bk + 16] = rb2;
    *(bf16x8*)&Bs[0][br][bk + 24] = rb3;

    for (int it = 0; it < nt; ++it) {
        __syncthreads();
        if (it + 1 < nt) {
            int ko = (it + 1) * 64;
            ra0 = *(const bf16x8*)(Ag + ko);
            ra1 = *(const bf16x8*)(Ag + ko + 8);
            rb0 = *(const bf16x8*)(Bg + ko);
            rb1 = *(const bf16x8*)(Bg + ko + 8);
            rb2 = *(const bf16x8*)(Bg + ko + 16);
            rb3 = *(const bf16x8*)(Bg + ko + 24);
        }
        #pragma unroll
        for (int ks = 0; ks < 2; ++ks) {
            int k0 = ks * 32 + lk * 8;
            bf16x8 af[2], bfr[4];
            #pragma unroll
            for (int i = 0; i < 2; ++i)
                af[i] = *(const bf16x8*)&As[cur][wr * 32 + i * 16 + lr][k0];
            #pragma unroll
            for (int j = 0; j < 4; ++j)
                bfr[j] = *(const bf16x8*)&Bs[cur][wc * 64 + j * 16 + lr][k0];
            #pragma unroll
            for (int i = 0; i < 2; ++i)
                #pragma unroll
                for (int j = 0; j < 4; ++j)
                    acc[i][j] = __builtin_amdgcn_mfma_f32_16x16x32_bf16(
                        af[i], bfr[j], acc[i][j], 0, 0, 0);
        }
        if (it + 1 < nt) {
            cur ^= 1;
            *(bf16x8*)&As[cur][ar][ak]      = ra0;
            *(bf16x8*)&As[cur][ar][ak + 8]  = ra1;
            *(bf16x8*)&Bs[cur][br][bk]      = rb0;
            *(bf16x8*)&Bs[cur][br][bk + 8]  = rb1;
            *(bf16x8*)&Bs[cur][br][bk + 16] = rb2;
            *(bf16x8*)&Bs[cur][br][bk + 24] = rb3;
        }
    }
    #pragma unroll
    for (int i = 0; i < 2; ++i) {
        #pragma unroll
        for (int r = 0; r < 4; ++r) {
            int gm = m0 + wr * 32 + i * 16 + lk * 4 + r;
            #pragma unroll
            for (int j = 0; j < 4; ++j) {
                int gn = n0 + wc * 64 + j * 16 + lr;
                Cp[(size_t)gm * ldc + gn] = acc[i][j][r];
            }
        }
    }
}

// === xt = (sum of 16 w-slabs)/sumE (or matched row) -> bf16 + norm + escale2 ===
__global__ __launch_bounds__(256)
void xt_fin(const float* __restrict__ wpart, const float* __restrict__ sumEp,
            const int* __restrict__ midx, const float* __restrict__ fromf,
            const float* __restrict__ fbar, const float* __restrict__ fms,
            short* __restrict__ xtb, float* __restrict__ xtn2,
            float* __restrict__ escale2)
{
    __shared__ float red[4];
    __shared__ float bc[1];
    int b = blockIdx.x;
    int t = threadIdx.x;
    int d = t * 2;
    int mi = midx[b];
    if (t == 0) {
        float s = 0.f;
        #pragma unroll
        for (int k = 0; k < 32; ++k) s += sumEp[(size_t)b * 32 + k];
        bc[0] = 1.0f / s;
    }
    float v0 = 0.f, v1 = 0.f;
    #pragma unroll
    for (int sl = 0; sl < 16; ++sl) {
        float2 p = *(const float2*)(wpart + (size_t)sl * (BB * DDIM) + (size_t)b * DDIM + d);
        v0 += p.x; v1 += p.y;
    }
    __syncthreads();
    float inv = bc[0];
    v0 *= inv; v1 *= inv;
    if (mi < NS) {
        v0 = fromf[(size_t)mi * DDIM + d];
        v1 = fromf[(size_t)mi * DDIM + d + 1];
    }
    xtb[(size_t)b * DDIM + d]     = f2bf(v0);
    xtb[(size_t)b * DDIM + d + 1] = f2bf(v1);
    float nt2 = block_sum(v0 * v0 + v1 * v1, red);
    float2 fb2 = *(const float2*)(fbar + d);
    float fd = block_sum(v0 * fb2.x + v1 * fb2.y, red);
    if (t == 0) {
        xtn2[b] = nt2;
        escale2[b] = -TEMP / (fms[0] + nt2 - 2.0f * fd);
    }
}

// =============== y_star from bf16 e2T: weighted one-hot average ===============
__global__ __launch_bounds__(256)
void ystar_fin(const short* __restrict__ e2T, const int* __restrict__ labels,
               float* __restrict__ out)
{
    __shared__ float cred[NCLS + 1][4];
    int b = blockIdx.x;
    int t = threadIdx.x;
    const short* row = e2T + (size_t)b * NS + t * 16;
    bf16x8 h0 = *(const bf16x8*)row;
    bf16x8 h1 = *(const bf16x8*)(row + 8);
    float accs[NCLS] = {};
    float te = 0.f;
    #pragma unroll
    for (int q = 0; q < 4; ++q) {
        int4 lb = *(const int4*)(labels + t * 16 + q * 4);
        int lbl[4] = {lb.x, lb.y, lb.z, lb.w};
        #pragma unroll
        for (int e = 0; e < 4; ++e) {
            int idx = q * 4 + e;
            float ev = bf2f(idx < 8 ? h0[idx] : h1[idx - 8]);
            te += ev;
            #pragma unroll
            for (int c = 0; c < NCLS; ++c) accs[c] += (lbl[e] == c) ? ev : 0.f;
        }
    }
    int wid = t >> 6, lane = t & 63;
    #pragma unroll
    for (int c = 0; c < NCLS + 1; ++c) {
        float sv = (c < NCLS) ? accs[c] : te;
        #pragma unroll
        for (int off = 32; off > 0; off >>= 1) sv += __shfl_down(sv, off);
        if (lane == 0) cred[c][wid] = sv;
    }
    __syncthreads();
    if (t < NCLS) {
        float num = cred[t][0] + cred[t][1] + cred[t][2] + cred[t][3];
        float den = cred[NCLS][0] + cred[NCLS][1] + cred[NCLS][2] + cred[NCLS][3];
        out[b * NCLS + t] = num / den;
    }
}

extern "C" void kernel_launch(void* const* d_in, const int* in_sizes, int n_in,
                              void* d_out, int out_size, void* d_ws, size_t ws_size,
                              hipStream_t stream) {
    const float* x     = (const float*)d_in[0];
    const float* star  = (const float*)d_in[1];
    const float* from  = (const float*)d_in[2];
    const int*   label = (const int*)d_in[3];
    float* out = (float*)d_out;

    float* F = (float*)d_ws;                     // ~40 MB of workspace
    float* wpart = F;                            // 16 x [512][512] f32 (16 MB)
    short* Sb    = (short*)(F + 4194304);        // star bf16  [4096][512]
    short* FTb   = (short*)(F + 5242880);        // fromT bf16 [512][4096]
    short* Fb    = (short*)(F + 6291456);        // from bf16  [4096][512]
    short* Eb    = (short*)(F + 7340032);        // eT bf16    [512][4096]
    short* E2b   = (short*)(F + 8388608);        // e2T bf16   [512][4096]
    short* Xb    = (short*)(F + 9437184);        // x bf16     [512][512]
    short* XTb   = (short*)(F + 9568256);        // xt bf16    [512][512]
    float* sn2   = F + 9699328;                  // 4096
    float* fn2   = F + 9703424;                  // 4096
    float* xn2   = F + 9707520;                  // 512
    float* xtn2  = F + 9708032;                  // 512
    float* esc1  = F + 9708544;                  // 512
    float* esc2  = F + 9709056;                  // 512
    float* sbar  = F + 9709568;                  // 512
    float* fbar  = F + 9710080;                  // 512
    float* sms   = F + 9710592;                  // 16
    float* fms   = F + 9710608;                  // 16
    float* sumEp = F + 9710624;                  // [512][32]
    float* scol  = F + 9727008;                  // 4096
    float* xcol  = F + 9731104;                  // 512
    int*   midx  = (int*)(F + 9731616);          // 512
    float* spart = F + 9732128;                  // [128][512]
    float* fpart = F + 9797664;                  // [128][512]

    prep<<<2944, 256, 0, stream>>>(x, star, from, Xb, Sb, FTb, Fb,
                                   xn2, sn2, fn2, scol, xcol, midx, spart, fpart);
    finmeans<<<2, 256, 0, stream>>>(spart, fpart, sn2, fn2, sbar, fbar, sms, fms);
    scale1<<<128, 256, 0, stream>>>(x, sbar, sms, xn2, esc1);
    match16<<<16, 256, 0, stream>>>(x, star, scol, xcol, midx);
    // eT[b][n] = bf16(exp(esc1[b]*clamp(xn2+sn2-2 x.star,0))) + sumE partials
    gemm_exp<1><<<dim3(8, 32), 256, 0, stream>>>(Xb, Sb, xn2, sn2, esc1, Eb, sumEp);
    // wpart[z][b][d] = sum_{n in slab z} eT[b][n]*fromT[d][n]
    gemm_bt<<<dim3(8, 4, 16), 256, 0, stream>>>(Eb, FTb, NS, 256, 4, wpart, DDIM,
                                                (size_t)BB * DDIM);
    xt_fin<<<BB, 256, 0, stream>>>(wpart, sumEp, midx, from, fbar, fms,
                                   XTb, xtn2, esc2);
    // e2T[b][n] = bf16(exp(esc2[b]*clamp(xtn2+fn2-2 xt.from,0)))
    gemm_exp<0><<<dim3(8, 32), 256, 0, stream>>>(XTb, Fb, xtn2, fn2, esc2, E2b, nullptr);
    ystar_fin<<<BB, 256, 0, stream>>>(E2b, label, out);
}

// Round 9
// 79.606 us; speedup vs baseline: 1.5239x; 1.0658x over previous
//
#include <hip/hip_runtime.h>

#define TEMP 10.0f
#define NS 4096
#define BB 512
#define DDIM 512
#define NCLS 10
#define LDSP 72

typedef short bf16x8 __attribute__((ext_vector_type(8)));
typedef float f32x4 __attribute__((ext_vector_type(4)));

__device__ inline short f2bf(float f) {
    unsigned u = __builtin_bit_cast(unsigned, f);
    u += 0x7FFFu + ((u >> 16) & 1u);      // round-to-nearest-even
    return (short)(u >> 16);
}
__device__ inline float bf2f(short h) {
    unsigned u = ((unsigned)(unsigned short)h) << 16;
    return __builtin_bit_cast(float, u);
}

// =============== block-wide sum helper (256 threads) ===============
__device__ inline float block_sum(float s, float* red) {
    #pragma unroll
    for (int off = 32; off > 0; off >>= 1) s += __shfl_down(s, off);
    int wid = threadIdx.x >> 6;
    if ((threadIdx.x & 63) == 0) red[wid] = s;
    __syncthreads();
    float tot = red[0] + red[1] + red[2] + red[3];
    __syncthreads();
    return tot;
}

// =============== prep: conversions / norms / col0 / colsum partials ===============
__global__ __launch_bounds__(256)
void prep(const float* __restrict__ x, const float* __restrict__ star,
          const float* __restrict__ from,
          short* __restrict__ Xb, short* __restrict__ Sb,
          short* __restrict__ FTb, short* __restrict__ Fb,
          float* __restrict__ xn2, float* __restrict__ sn2, float* __restrict__ fn2,
          float* __restrict__ scol, float* __restrict__ xcol, int* __restrict__ midx,
          float* __restrict__ spart, float* __restrict__ fpart)
{
    int bid = blockIdx.x, t = threadIdx.x;
    if (bid < 2176) {
        const float* in; short* outb; float* n2; float* colb; int rowbase;
        if (bid < 1024)      { in = star; outb = Sb; n2 = sn2; colb = scol; rowbase = bid * 4; }
        else if (bid < 1152) { in = x;    outb = Xb; n2 = xn2; colb = xcol; rowbase = (bid - 1024) * 4; }
        else                 { in = from; outb = Fb; n2 = fn2; colb = nullptr; rowbase = (bid - 1152) * 4; }
        if (bid == 1024) { midx[t] = NS; midx[256 + t] = NS; }
        int row = rowbase + (t >> 6);
        int l = t & 63;
        const float4* p = (const float4*)(in + (size_t)row * DDIM) + l * 2;
        float4 a = p[0], b = p[1];
        float s = a.x*a.x + a.y*a.y + a.z*a.z + a.w*a.w
                + b.x*b.x + b.y*b.y + b.z*b.z + b.w*b.w;
        bf16x8 h;
        h[0]=f2bf(a.x); h[1]=f2bf(a.y); h[2]=f2bf(a.z); h[3]=f2bf(a.w);
        h[4]=f2bf(b.x); h[5]=f2bf(b.y); h[6]=f2bf(b.z); h[7]=f2bf(b.w);
        *(bf16x8*)(outb + (size_t)row * DDIM + l * 8) = h;
        #pragma unroll
        for (int off = 32; off > 0; off >>= 1) s += __shfl_down(s, off);
        if (l == 0) {
            n2[row] = s;
            if (colb) colb[row] = a.x;
        }
        return;
    }
    if (bid >= 2688) {
        // ---- coalesced 32-row column-sum partial ----
        __shared__ float cp[512];
        int ib = bid - 2688;                  // 0..255
        const float* M = (ib < 128) ? star : from;
        float* part = (ib < 128) ? spart : fpart;
        int r0 = (ib & 127) * 32;
        int c4 = (t & 127) * 4, rg = t >> 7;
        float4 acc = {0.f, 0.f, 0.f, 0.f};
        #pragma unroll 4
        for (int r = rg; r < 32; r += 2) {
            float4 v = *(const float4*)(M + (size_t)(r0 + r) * DDIM + c4);
            acc.x += v.x; acc.y += v.y; acc.z += v.z; acc.w += v.w;
        }
        if (rg == 1) *(float4*)&cp[c4] = acc;
        __syncthreads();
        if (rg == 0) {
            float4 o = *(const float4*)&cp[c4];
            acc.x += o.x; acc.y += o.y; acc.z += o.z; acc.w += o.w;
            *(float4*)&part[(size_t)(ib & 127) * 512 + c4] = acc;
        }
        return;
    }
    // ---- from transpose tile ----
    __shared__ short tile[64][LDSP];
    int tid2 = bid - 2176;
    int n0 = (tid2 & 63) * 64, d0 = (tid2 >> 6) * 64;
    int r = t >> 4, c4 = (t & 15) * 4;
    #pragma unroll
    for (int rr = 0; rr < 64; rr += 16) {
        float4 v = *(const float4*)(from + (size_t)(n0 + r + rr) * DDIM + d0 + c4);
        tile[r + rr][c4 + 0] = f2bf(v.x);
        tile[r + rr][c4 + 1] = f2bf(v.y);
        tile[r + rr][c4 + 2] = f2bf(v.z);
        tile[r + rr][c4 + 3] = f2bf(v.w);
    }
    __syncthreads();
    int dr = t >> 2, nco = (t & 3) * 16;
    short tmp[16];
    #pragma unroll
    for (int q = 0; q < 16; ++q) tmp[q] = tile[nco + q][dr];
    short* op = FTb + (size_t)(d0 + dr) * NS + n0 + nco;
    *(bf16x8*)op       = *(bf16x8*)tmp;
    *(bf16x8*)(op + 8) = *(bf16x8*)(tmp + 8);
}

// ===== finmeans: 2 blocks. Reduce colsum partials -> sbar/fbar; mean(n2) -> sms/fms =====
__global__ __launch_bounds__(256)
void finmeans(const float* __restrict__ spart, const float* __restrict__ fpart,
              const float* __restrict__ sn2, const float* __restrict__ fn2,
              float* __restrict__ sbar, float* __restrict__ fbar,
              float* __restrict__ sms, float* __restrict__ fms)
{
    __shared__ float red[4];
    int bid = blockIdx.x, t = threadIdx.x;
    const float* part = bid ? fpart : spart;
    const float* n2v  = bid ? fn2 : sn2;
    float* outm = bid ? fbar : sbar;
    float* outs = bid ? fms : sms;
    float ax = 0.f, ay = 0.f;
    #pragma unroll 8
    for (int k = 0; k < 128; ++k) {
        float2 v = *(const float2*)(part + (size_t)k * 512 + t * 2);
        ax += v.x; ay += v.y;
    }
    float2 o; o.x = ax * (1.0f / NS); o.y = ay * (1.0f / NS);
    *(float2*)(outm + t * 2) = o;
    float s = 0.f;
    #pragma unroll
    for (int q = 0; q < 16; ++q) s += n2v[q * 256 + t];
    float tot = block_sum(s, red);
    if (t == 0) outs[0] = tot * (1.0f / NS);
}

// ===== aux: blocks [0,128) -> escale1; blocks [128,144) -> exact-match scan =====
__global__ __launch_bounds__(256)
void aux(const float* __restrict__ x, const float* __restrict__ star,
         const float* __restrict__ sbar, const float* __restrict__ sms,
         const float* __restrict__ xn2, float* __restrict__ escale1,
         const float* __restrict__ scol, const float* __restrict__ xcol,
         int* __restrict__ midx)
{
    int bid = blockIdx.x, t = threadIdx.x;
    if (bid < 128) {
        int lane = t & 63, w = t >> 6;
        int b = bid * 4 + w;
        const float4* xp = (const float4*)(x + (size_t)b * DDIM) + lane * 2;
        const float4* sp = (const float4*)sbar + lane * 2;
        float4 xa = xp[0], xb = xp[1], sa = sp[0], sb = sp[1];
        float dot = xa.x*sa.x + xa.y*sa.y + xa.z*sa.z + xa.w*sa.w
                  + xb.x*sb.x + xb.y*sb.y + xb.z*sb.z + xb.w*sb.w;
        #pragma unroll
        for (int m = 32; m > 0; m >>= 1) dot += __shfl_xor(dot, m);
        if (lane == 0)
            escale1[b] = -TEMP / (sms[0] + xn2[b] - 2.0f * dot);
        return;
    }
    __shared__ float xl[BB];
    *(float2*)&xl[t * 2] = *(const float2*)&xcol[t * 2];
    __syncthreads();
    int n = (bid - 128) * 256 + t;
    float sv = scol[n];
    #pragma unroll 4
    for (int b4 = 0; b4 < BB; b4 += 4) {
        float4 xv = *(const float4*)&xl[b4];
        if (xv.x == sv || xv.y == sv || xv.z == sv || xv.w == sv) {
            #pragma unroll
            for (int j = 0; j < 4; ++j) {
                int b = b4 + j;
                if (xl[b] == sv) {
                    const float* xr = x + (size_t)b * DDIM;
                    const float* sr = star + (size_t)n * DDIM;
                    bool eq = true;
                    for (int k = 0; k < DDIM && eq; k += 4) {
                        float4 a = *(const float4*)(xr + k);
                        float4 c = *(const float4*)(sr + k);
                        eq = (a.x == c.x) && (a.y == c.y) &&
                             (a.z == c.z) && (a.w == c.w);
                    }
                    if (eq) atomicMin(&midx[b], n);
                }
            }
        }
    }
}

// ====== MFMA GEMM + fused sqdist/exp epilogue -> bf16 E (8 waves, 512 thr) ======
// Wave grid 2x4 over the 64x128 tile; per-wave acc[2][2]. 2 blocks/CU (110KB LDS).
template<int WSE>
__global__ __launch_bounds__(512)
void gemm_exp(const short* __restrict__ A, const short* __restrict__ B,
              const float* __restrict__ an2, const float* __restrict__ bn2,
              const float* __restrict__ escale, short* __restrict__ Eout,
              float* __restrict__ sumEp)
{
    __shared__ short As[2][64][LDSP];
    __shared__ short Bs[2][128][LDSP];
    __shared__ float se[4][64];
    const int K = DDIM;
    int t = threadIdx.x;
    int m0 = blockIdx.x * 64;
    int n0 = blockIdx.y * 128;
    int wid = t >> 6, lane = t & 63;
    int wr = wid >> 2, wc = wid & 3;      // 2 x 4 waves
    int lr = lane & 15, lk = lane >> 4;

    int ar = t >> 3, ak = (t & 7) * 8;    // A: 64 rows x 64 shorts, 8/thread
    int br = t >> 2, bk = (t & 3) * 16;   // B: 128 rows x 64 shorts, 16/thread
    const short* Ag = A + (size_t)(m0 + ar) * K + ak;
    const short* Bg = B + (size_t)(n0 + br) * K + bk;

    f32x4 acc[2][2] = {};
    bf16x8 ra0 = *(const bf16x8*)Ag;
    bf16x8 rb0 = *(const bf16x8*)Bg;
    bf16x8 rb1 = *(const bf16x8*)(Bg + 8);
    int cur = 0;
    *(bf16x8*)&As[0][ar][ak]     = ra0;
    *(bf16x8*)&Bs[0][br][bk]     = rb0;
    *(bf16x8*)&Bs[0][br][bk + 8] = rb1;

    const int nt = K / 64;
    for (int it = 0; it < nt; ++it) {
        __syncthreads();
        if (it + 1 < nt) {
            int ko = (it + 1) * 64;
            ra0 = *(const bf16x8*)(Ag + ko);
            rb0 = *(const bf16x8*)(Bg + ko);
            rb1 = *(const bf16x8*)(Bg + ko + 8);
        }
        #pragma unroll
        for (int ks = 0; ks < 2; ++ks) {
            int k0 = ks * 32 + lk * 8;
            bf16x8 af[2], bfr[2];
            #pragma unroll
            for (int i = 0; i < 2; ++i)
                af[i] = *(const bf16x8*)&As[cur][wr * 32 + i * 16 + lr][k0];
            #pragma unroll
            for (int j = 0; j < 2; ++j)
                bfr[j] = *(const bf16x8*)&Bs[cur][wc * 32 + j * 16 + lr][k0];
            #pragma unroll
            for (int i = 0; i < 2; ++i)
                #pragma unroll
                for (int j = 0; j < 2; ++j)
                    acc[i][j] = __builtin_amdgcn_mfma_f32_16x16x32_bf16(
                        af[i], bfr[j], acc[i][j], 0, 0, 0);
        }
        if (it + 1 < nt) {
            cur ^= 1;
            *(bf16x8*)&As[cur][ar][ak]     = ra0;
            *(bf16x8*)&Bs[cur][br][bk]     = rb0;
            *(bf16x8*)&Bs[cur][br][bk + 8] = rb1;
        }
    }
    // ---- epilogue: clamp + exp + bf16 store (+ per-block sumE partials) ----
    float bn2v[2];
    int gnv[2];
    #pragma unroll
    for (int j = 0; j < 2; ++j) { gnv[j] = n0 + wc * 32 + j * 16 + lr; bn2v[j] = bn2[gnv[j]]; }
    #pragma unroll
    for (int i = 0; i < 2; ++i) {
        #pragma unroll
        for (int r = 0; r < 4; ++r) {
            int gm = m0 + wr * 32 + i * 16 + lk * 4 + r;
            float a2 = an2[gm];
            float sc = escale[gm];
            float rs = 0.f;
            #pragma unroll
            for (int j = 0; j < 2; ++j) {
                float dv = fmaxf(a2 + bn2v[j] - 2.0f * acc[i][j][r], 0.0f);
                short hb = f2bf(__expf(dv * sc));
                Eout[(size_t)gm * NS + gnv[j]] = hb;
                if (WSE) rs += bf2f(hb);
            }
            if (WSE) {
                #pragma unroll
                for (int m = 1; m < 16; m <<= 1) rs += __shfl_xor(rs, m);
                if (lr == 0) se[wc][wr * 32 + i * 16 + lk * 4 + r] = rs;
            }
        }
    }
    if (WSE) {
        __syncthreads();
        if (t < 64)
            sumEp[(size_t)(m0 + t) * 32 + blockIdx.y] =
                se[0][t] + se[1][t] + se[2][t] + se[3][t];
    }
}

// =============== MFMA GEMM raw partials (for w = e @ fromT, K-split) ===============
__global__ __launch_bounds__(256)
void gemm_bt(const short* __restrict__ A, const short* __restrict__ B, int K,
             int kslab, int nt, float* __restrict__ C, int ldc, size_t cstride)
{
    __shared__ short As[2][64][LDSP];
    __shared__ short Bs[2][128][LDSP];
    int t = threadIdx.x;
    int m0 = blockIdx.x * 64;
    int n0 = blockIdx.y * 128;
    int kbase = blockIdx.z * kslab;
    float* Cp = C + (size_t)blockIdx.z * cstride;
    int wid = t >> 6, lane = t & 63;
    int wr = wid >> 1, wc = wid & 1;
    int lr = lane & 15, lk = lane >> 4;

    int ar = t >> 2, ak = (t & 3) * 16;
    int br = t >> 1, bk = (t & 1) * 32;
    const short* Ag = A + (size_t)(m0 + ar) * K + kbase + ak;
    const short* Bg = B + (size_t)(n0 + br) * K + kbase + bk;

    f32x4 acc[2][4] = {};
    bf16x8 ra0 = *(const bf16x8*)Ag;
    bf16x8 ra1 = *(const bf16x8*)(Ag + 8);
    bf16x8 rb0 = *(const bf16x8*)Bg;
    bf16x8 rb1 = *(const bf16x8*)(Bg + 8);
    bf16x8 rb2 = *(const bf16x8*)(Bg + 16);
    bf16x8 rb3 = *(const bf16x8*)(Bg + 24);
    int cur = 0;
    *(bf16x8*)&As[0][ar][ak]      = ra0;
    *(bf16x8*)&As[0][ar][ak + 8]  = ra1;
    *(bf16x8*)&Bs[0][br][bk]      = rb0;
    *(bf16x8*)&Bs[0][br][bk + 8]  = rb1;
    *(bf16x8*)&Bs[0][br][bk + 16] = rb2;
    *(bf16x8*)&Bs[0][br][bk + 24] = rb3;

    for (int it = 0; it < nt; ++it) {
        __syncthreads();
        if (it + 1 < nt) {
            int ko = (it + 1) * 64;
            ra0 = *(const bf16x8*)(Ag + ko);
            ra1 = *(const bf16x8*)(Ag + ko + 8);
            rb0 = *(const bf16x8*)(Bg + ko);
            rb1 = *(const bf16x8*)(Bg + ko + 8);
            rb2 = *(const bf16x8*)(Bg + ko + 16);
            rb3 = *(const bf16x8*)(Bg + ko + 24);
        }
        #pragma unroll
        for (int ks = 0; ks < 2; ++ks) {
            int k0 = ks * 32 + lk * 8;
            bf16x8 af[2], bfr[4];
            #pragma unroll
            for (int i = 0; i < 2; ++i)
                af[i] = *(const bf16x8*)&As[cur][wr * 32 + i * 16 + lr][k0];
            #pragma unroll
            for (int j = 0; j < 4; ++j)
                bfr[j] = *(const bf16x8*)&Bs[cur][wc * 64 + j * 16 + lr][k0];
            #pragma unroll
            for (int i = 0; i < 2; ++i)
                #pragma unroll
                for (int j = 0; j < 4; ++j)
                    acc[i][j] = __builtin_amdgcn_mfma_f32_16x16x32_bf16(
                        af[i], bfr[j], acc[i][j], 0, 0, 0);
        }
        if (it + 1 < nt) {
            cur ^= 1;
            *(bf16x8*)&As[cur][ar][ak]      = ra0;
            *(bf16x8*)&As[cur][ar][ak + 8]  = ra1;
            *(bf16x8*)&Bs[cur][br][bk]      = rb0;
            *(bf16x8*)&Bs[cur][br][bk + 8]  = rb1;
            *(bf16x8*)&Bs[cur][br][bk + 16] = rb2;
            *(bf16x8*)&Bs[cur][br][bk + 24] = rb3;
        }
    }
    #pragma unroll
    for (int i = 0; i < 2; ++i) {
        #pragma unroll
        for (int r = 0; r < 4; ++r) {
            int gm = m0 + wr * 32 + i * 16 + lk * 4 + r;
            #pragma unroll
            for (int j = 0; j < 4; ++j) {
                int gn = n0 + wc * 64 + j * 16 + lr;
                Cp[(size_t)gm * ldc + gn] = acc[i][j][r];
            }
        }
    }
}

// === xt = (sum of 16 w-slabs)/sumE (or matched row) -> bf16 + norm + escale2 ===
__global__ __launch_bounds__(256)
void xt_fin(const float* __restrict__ wpart, const float* __restrict__ sumEp,
            const int* __restrict__ midx, const float* __restrict__ fromf,
            const float* __restrict__ fbar, const float* __restrict__ fms,
            short* __restrict__ xtb, float* __restrict__ xtn2,
            float* __restrict__ escale2)
{
    __shared__ float red[4];
    __shared__ float bc[1];
    int b = blockIdx.x;
    int t = threadIdx.x;
    int d = t * 2;
    int mi = midx[b];
    if (t == 0) {
        float s = 0.f;
        #pragma unroll
        for (int k = 0; k < 32; ++k) s += sumEp[(size_t)b * 32 + k];
        bc[0] = 1.0f / s;
    }
    float v0 = 0.f, v1 = 0.f;
    #pragma unroll
    for (int sl = 0; sl < 16; ++sl) {
        float2 p = *(const float2*)(wpart + (size_t)sl * (BB * DDIM) + (size_t)b * DDIM + d);
        v0 += p.x; v1 += p.y;
    }
    __syncthreads();
    float inv = bc[0];
    v0 *= inv; v1 *= inv;
    if (mi < NS) {
        v0 = fromf[(size_t)mi * DDIM + d];
        v1 = fromf[(size_t)mi * DDIM + d + 1];
    }
    xtb[(size_t)b * DDIM + d]     = f2bf(v0);
    xtb[(size_t)b * DDIM + d + 1] = f2bf(v1);
    float nt2 = block_sum(v0 * v0 + v1 * v1, red);
    float2 fb2 = *(const float2*)(fbar + d);
    float fd = block_sum(v0 * fb2.x + v1 * fb2.y, red);
    if (t == 0) {
        xtn2[b] = nt2;
        escale2[b] = -TEMP / (fms[0] + nt2 - 2.0f * fd);
    }
}

// =============== y_star from bf16 e2T: weighted one-hot average ===============
__global__ __launch_bounds__(256)
void ystar_fin(const short* __restrict__ e2T, const int* __restrict__ labels,
               float* __restrict__ out)
{
    __shared__ float cred[NCLS + 1][4];
    int b = blockIdx.x;
    int t = threadIdx.x;
    const short* row = e2T + (size_t)b * NS + t * 16;
    bf16x8 h0 = *(const bf16x8*)row;
    bf16x8 h1 = *(const bf16x8*)(row + 8);
    float accs[NCLS] = {};
    float te = 0.f;
    #pragma unroll
    for (int q = 0; q < 4; ++q) {
        int4 lb = *(const int4*)(labels + t * 16 + q * 4);
        int lbl[4] = {lb.x, lb.y, lb.z, lb.w};
        #pragma unroll
        for (int e = 0; e < 4; ++e) {
            int idx = q * 4 + e;
            float ev = bf2f(idx < 8 ? h0[idx] : h1[idx - 8]);
            te += ev;
            #pragma unroll
            for (int c = 0; c < NCLS; ++c) accs[c] += (lbl[e] == c) ? ev : 0.f;
        }
    }
    int wid = t >> 6, lane = t & 63;
    #pragma unroll
    for (int c = 0; c < NCLS + 1; ++c) {
        float sv = (c < NCLS) ? accs[c] : te;
        #pragma unroll
        for (int off = 32; off > 0; off >>= 1) sv += __shfl_down(sv, off);
        if (lane == 0) cred[c][wid] = sv;
    }
    __syncthreads();
    if (t < NCLS) {
        float num = cred[t][0] + cred[t][1] + cred[t][2] + cred[t][3];
        float den = cred[NCLS][0] + cred[NCLS][1] + cred[NCLS][2] + cred[NCLS][3];
        out[b * NCLS + t] = num / den;
    }
}

extern "C" void kernel_launch(void* const* d_in, const int* in_sizes, int n_in,
                              void* d_out, int out_size, void* d_ws, size_t ws_size,
                              hipStream_t stream) {
    const float* x     = (const float*)d_in[0];
    const float* star  = (const float*)d_in[1];
    const float* from  = (const float*)d_in[2];
    const int*   label = (const int*)d_in[3];
    float* out = (float*)d_out;

    float* F = (float*)d_ws;                     // ~40 MB of workspace
    float* wpart = F;                            // 16 x [512][512] f32 (16 MB)
    short* Sb    = (short*)(F + 4194304);        // star bf16  [4096][512]
    short* FTb   = (short*)(F + 5242880);        // fromT bf16 [512][4096]
    short* Fb    = (short*)(F + 6291456);        // from bf16  [4096][512]
    short* Eb    = (short*)(F + 7340032);        // eT bf16    [512][4096]
    short* E2b   = (short*)(F + 8388608);        // e2T bf16   [512][4096]
    short* Xb    = (short*)(F + 9437184);        // x bf16     [512][512]
    short* XTb   = (short*)(F + 9568256);        // xt bf16    [512][512]
    float* sn2   = F + 9699328;                  // 4096
    float* fn2   = F + 9703424;                  // 4096
    float* xn2   = F + 9707520;                  // 512
    float* xtn2  = F + 9708032;                  // 512
    float* esc1  = F + 9708544;                  // 512
    float* esc2  = F + 9709056;                  // 512
    float* sbar  = F + 9709568;                  // 512
    float* fbar  = F + 9710080;                  // 512
    float* sms   = F + 9710592;                  // 16
    float* fms   = F + 9710608;                  // 16
    float* sumEp = F + 9710624;                  // [512][32]
    float* scol  = F + 9727008;                  // 4096
    float* xcol  = F + 9731104;                  // 512
    int*   midx  = (int*)(F + 9731616);          // 512
    float* spart = F + 9732128;                  // [128][512]
    float* fpart = F + 9797664;                  // [128][512]

    prep<<<2944, 256, 0, stream>>>(x, star, from, Xb, Sb, FTb, Fb,
                                   xn2, sn2, fn2, scol, xcol, midx, spart, fpart);
    finmeans<<<2, 256, 0, stream>>>(spart, fpart, sn2, fn2, sbar, fbar, sms, fms);
    aux<<<144, 256, 0, stream>>>(x, star, sbar, sms, xn2, esc1, scol, xcol, midx);
    // eT[b][n] = bf16(exp(esc1[b]*clamp(xn2+sn2-2 x.star,0))) + sumE partials
    gemm_exp<1><<<dim3(8, 32), 512, 0, stream>>>(Xb, Sb, xn2, sn2, esc1, Eb, sumEp);
    // wpart[z][b][d] = sum_{n in slab z} eT[b][n]*fromT[d][n]
    gemm_bt<<<dim3(8, 4, 16), 256, 0, stream>>>(Eb, FTb, NS, 256, 4, wpart, DDIM,
                                                (size_t)BB * DDIM);
    xt_fin<<<BB, 256, 0, stream>>>(wpart, sumEp, midx, from, fbar, fms,
                                   XTb, xtn2, esc2);
    // e2T[b][n] = bf16(exp(esc2[b]*clamp(xtn2+fn2-2 xt.from,0)))
    gemm_exp<0><<<dim3(8, 32), 512, 0, stream>>>(XTb, Fb, xtn2, fn2, esc2, E2b, nullptr);
    ystar_fin<<<BB, 256, 0, stream>>>(E2b, label, out);
}

// Round 10
// 79.429 us; speedup vs baseline: 1.5273x; 1.0022x over previous
//
#include <hip/hip_runtime.h>

#define TEMP 10.0f
#define NS 4096
#define BB 512
#define DDIM 512
#define NCLS 10
#define LDSP 72

typedef short bf16x8 __attribute__((ext_vector_type(8)));
typedef float f32x4 __attribute__((ext_vector_type(4)));

__device__ inline short f2bf(float f) {
    unsigned u = __builtin_bit_cast(unsigned, f);
    u += 0x7FFFu + ((u >> 16) & 1u);      // round-to-nearest-even
    return (short)(u >> 16);
}
__device__ inline float bf2f(short h) {
    unsigned u = ((unsigned)(unsigned short)h) << 16;
    return __builtin_bit_cast(float, u);
}

// =============== block-wide sum helper (256 threads) ===============
__device__ inline float block_sum(float s, float* red) {
    #pragma unroll
    for (int off = 32; off > 0; off >>= 1) s += __shfl_down(s, off);
    int wid = threadIdx.x >> 6;
    if ((threadIdx.x & 63) == 0) red[wid] = s;
    __syncthreads();
    float tot = red[0] + red[1] + red[2] + red[3];
    __syncthreads();
    return tot;
}

// =============== prep: conversions / norms / col0 / colsum partials ===============
__global__ __launch_bounds__(256)
void prep(const float* __restrict__ x, const float* __restrict__ star,
          const float* __restrict__ from,
          short* __restrict__ Xb, short* __restrict__ Sb,
          short* __restrict__ FTb, short* __restrict__ Fb,
          float* __restrict__ xn2, float* __restrict__ sn2, float* __restrict__ fn2,
          float* __restrict__ scol, float* __restrict__ xcol, int* __restrict__ midx,
          float* __restrict__ spart, float* __restrict__ fpart)
{
    int bid = blockIdx.x, t = threadIdx.x;
    if (bid < 2176) {
        const float* in; short* outb; float* n2; float* colb; int rowbase;
        if (bid < 1024)      { in = star; outb = Sb; n2 = sn2; colb = scol; rowbase = bid * 4; }
        else if (bid < 1152) { in = x;    outb = Xb; n2 = xn2; colb = xcol; rowbase = (bid - 1024) * 4; }
        else                 { in = from; outb = Fb; n2 = fn2; colb = nullptr; rowbase = (bid - 1152) * 4; }
        if (bid == 1024) { midx[t] = NS; midx[256 + t] = NS; }
        int row = rowbase + (t >> 6);
        int l = t & 63;
        const float4* p = (const float4*)(in + (size_t)row * DDIM) + l * 2;
        float4 a = p[0], b = p[1];
        float s = a.x*a.x + a.y*a.y + a.z*a.z + a.w*a.w
                + b.x*b.x + b.y*b.y + b.z*b.z + b.w*b.w;
        bf16x8 h;
        h[0]=f2bf(a.x); h[1]=f2bf(a.y); h[2]=f2bf(a.z); h[3]=f2bf(a.w);
        h[4]=f2bf(b.x); h[5]=f2bf(b.y); h[6]=f2bf(b.z); h[7]=f2bf(b.w);
        *(bf16x8*)(outb + (size_t)row * DDIM + l * 8) = h;
        #pragma unroll
        for (int off = 32; off > 0; off >>= 1) s += __shfl_down(s, off);
        if (l == 0) {
            n2[row] = s;
            if (colb) colb[row] = a.x;
        }
        return;
    }
    if (bid >= 2688) {
        // ---- coalesced 32-row column-sum partial ----
        __shared__ float cp[512];
        int ib = bid - 2688;                  // 0..255
        const float* M = (ib < 128) ? star : from;
        float* part = (ib < 128) ? spart : fpart;
        int r0 = (ib & 127) * 32;
        int c4 = (t & 127) * 4, rg = t >> 7;
        float4 acc = {0.f, 0.f, 0.f, 0.f};
        #pragma unroll 4
        for (int r = rg; r < 32; r += 2) {
            float4 v = *(const float4*)(M + (size_t)(r0 + r) * DDIM + c4);
            acc.x += v.x; acc.y += v.y; acc.z += v.z; acc.w += v.w;
        }
        if (rg == 1) *(float4*)&cp[c4] = acc;
        __syncthreads();
        if (rg == 0) {
            float4 o = *(const float4*)&cp[c4];
            acc.x += o.x; acc.y += o.y; acc.z += o.z; acc.w += o.w;
            *(float4*)&part[(size_t)(ib & 127) * 512 + c4] = acc;
        }
        return;
    }
    // ---- from transpose tile ----
    __shared__ short tile[64][LDSP];
    int tid2 = bid - 2176;
    int n0 = (tid2 & 63) * 64, d0 = (tid2 >> 6) * 64;
    int r = t >> 4, c4 = (t & 15) * 4;
    #pragma unroll
    for (int rr = 0; rr < 64; rr += 16) {
        float4 v = *(const float4*)(from + (size_t)(n0 + r + rr) * DDIM + d0 + c4);
        tile[r + rr][c4 + 0] = f2bf(v.x);
        tile[r + rr][c4 + 1] = f2bf(v.y);
        tile[r + rr][c4 + 2] = f2bf(v.z);
        tile[r + rr][c4 + 3] = f2bf(v.w);
    }
    __syncthreads();
    int dr = t >> 2, nco = (t & 3) * 16;
    short tmp[16];
    #pragma unroll
    for (int q = 0; q < 16; ++q) tmp[q] = tile[nco + q][dr];
    short* op = FTb + (size_t)(d0 + dr) * NS + n0 + nco;
    *(bf16x8*)op       = *(bf16x8*)tmp;
    *(bf16x8*)(op + 8) = *(bf16x8*)(tmp + 8);
}

// ===== finmeans: 2 blocks. Reduce colsum partials -> sbar/fbar; mean(n2) -> sms/fms =====
__global__ __launch_bounds__(256)
void finmeans(const float* __restrict__ spart, const float* __restrict__ fpart,
              const float* __restrict__ sn2, const float* __restrict__ fn2,
              float* __restrict__ sbar, float* __restrict__ fbar,
              float* __restrict__ sms, float* __restrict__ fms)
{
    __shared__ float red[4];
    int bid = blockIdx.x, t = threadIdx.x;
    const float* part = bid ? fpart : spart;
    const float* n2v  = bid ? fn2 : sn2;
    float* outm = bid ? fbar : sbar;
    float* outs = bid ? fms : sms;
    float ax = 0.f, ay = 0.f;
    #pragma unroll 8
    for (int k = 0; k < 128; ++k) {
        float2 v = *(const float2*)(part + (size_t)k * 512 + t * 2);
        ax += v.x; ay += v.y;
    }
    float2 o; o.x = ax * (1.0f / NS); o.y = ay * (1.0f / NS);
    *(float2*)(outm + t * 2) = o;
    float s = 0.f;
    #pragma unroll
    for (int q = 0; q < 16; ++q) s += n2v[q * 256 + t];
    float tot = block_sum(s, red);
    if (t == 0) outs[0] = tot * (1.0f / NS);
}

// ===== aux: blocks [0,128) -> escale1; blocks [128,144) -> exact-match scan =====
__global__ __launch_bounds__(256)
void aux(const float* __restrict__ x, const float* __restrict__ star,
         const float* __restrict__ sbar, const float* __restrict__ sms,
         const float* __restrict__ xn2, float* __restrict__ escale1,
         const float* __restrict__ scol, const float* __restrict__ xcol,
         int* __restrict__ midx)
{
    int bid = blockIdx.x, t = threadIdx.x;
    if (bid < 128) {
        int lane = t & 63, w = t >> 6;
        int b = bid * 4 + w;
        const float4* xp = (const float4*)(x + (size_t)b * DDIM) + lane * 2;
        const float4* sp = (const float4*)sbar + lane * 2;
        float4 xa = xp[0], xb = xp[1], sa = sp[0], sb = sp[1];
        float dot = xa.x*sa.x + xa.y*sa.y + xa.z*sa.z + xa.w*sa.w
                  + xb.x*sb.x + xb.y*sb.y + xb.z*sb.z + xb.w*sb.w;
        #pragma unroll
        for (int m = 32; m > 0; m >>= 1) dot += __shfl_xor(dot, m);
        if (lane == 0)
            escale1[b] = -TEMP / (sms[0] + xn2[b] - 2.0f * dot);
        return;
    }
    __shared__ float xl[BB];
    *(float2*)&xl[t * 2] = *(const float2*)&xcol[t * 2];
    __syncthreads();
    int n = (bid - 128) * 256 + t;
    float sv = scol[n];
    #pragma unroll 4
    for (int b4 = 0; b4 < BB; b4 += 4) {
        float4 xv = *(const float4*)&xl[b4];
        if (xv.x == sv || xv.y == sv || xv.z == sv || xv.w == sv) {
            #pragma unroll
            for (int j = 0; j < 4; ++j) {
                int b = b4 + j;
                if (xl[b] == sv) {
                    const float* xr = x + (size_t)b * DDIM;
                    const float* sr = star + (size_t)n * DDIM;
                    bool eq = true;
                    for (int k = 0; k < DDIM && eq; k += 4) {
                        float4 a = *(const float4*)(xr + k);
                        float4 c = *(const float4*)(sr + k);
                        eq = (a.x == c.x) && (a.y == c.y) &&
                             (a.z == c.z) && (a.w == c.w);
                    }
                    if (eq) atomicMin(&midx[b], n);
                }
            }
        }
    }
}

// ====== MFMA GEMM + fused sqdist/exp epilogue -> bf16 E (8 waves, 512 thr) ======
template<int WSE>
__global__ __launch_bounds__(512)
void gemm_exp(const short* __restrict__ A, const short* __restrict__ B,
              const float* __restrict__ an2, const float* __restrict__ bn2,
              const float* __restrict__ escale, short* __restrict__ Eout,
              float* __restrict__ sumEp)
{
    __shared__ short As[2][64][LDSP];
    __shared__ short Bs[2][128][LDSP];
    __shared__ float se[4][64];
    const int K = DDIM;
    int t = threadIdx.x;
    int m0 = blockIdx.x * 64;
    int n0 = blockIdx.y * 128;
    int wid = t >> 6, lane = t & 63;
    int wr = wid >> 2, wc = wid & 3;      // 2 x 4 waves
    int lr = lane & 15, lk = lane >> 4;

    int ar = t >> 3, ak = (t & 7) * 8;    // A: 64 rows x 64 shorts, 8/thread
    int br = t >> 2, bk = (t & 3) * 16;   // B: 128 rows x 64 shorts, 16/thread
    const short* Ag = A + (size_t)(m0 + ar) * K + ak;
    const short* Bg = B + (size_t)(n0 + br) * K + bk;

    f32x4 acc[2][2] = {};
    bf16x8 ra0 = *(const bf16x8*)Ag;
    bf16x8 rb0 = *(const bf16x8*)Bg;
    bf16x8 rb1 = *(const bf16x8*)(Bg + 8);
    int cur = 0;
    *(bf16x8*)&As[0][ar][ak]     = ra0;
    *(bf16x8*)&Bs[0][br][bk]     = rb0;
    *(bf16x8*)&Bs[0][br][bk + 8] = rb1;

    const int nt = K / 64;
    for (int it = 0; it < nt; ++it) {
        __syncthreads();
        if (it + 1 < nt) {
            int ko = (it + 1) * 64;
            ra0 = *(const bf16x8*)(Ag + ko);
            rb0 = *(const bf16x8*)(Bg + ko);
            rb1 = *(const bf16x8*)(Bg + ko + 8);
        }
        #pragma unroll
        for (int ks = 0; ks < 2; ++ks) {
            int k0 = ks * 32 + lk * 8;
            bf16x8 af[2], bfr[2];
            #pragma unroll
            for (int i = 0; i < 2; ++i)
                af[i] = *(const bf16x8*)&As[cur][wr * 32 + i * 16 + lr][k0];
            #pragma unroll
            for (int j = 0; j < 2; ++j)
                bfr[j] = *(const bf16x8*)&Bs[cur][wc * 32 + j * 16 + lr][k0];
            #pragma unroll
            for (int i = 0; i < 2; ++i)
                #pragma unroll
                for (int j = 0; j < 2; ++j)
                    acc[i][j] = __builtin_amdgcn_mfma_f32_16x16x32_bf16(
                        af[i], bfr[j], acc[i][j], 0, 0, 0);
        }
        if (it + 1 < nt) {
            cur ^= 1;
            *(bf16x8*)&As[cur][ar][ak]     = ra0;
            *(bf16x8*)&Bs[cur][br][bk]     = rb0;
            *(bf16x8*)&Bs[cur][br][bk + 8] = rb1;
        }
    }
    // ---- epilogue: clamp + exp + bf16 store (+ per-block sumE partials) ----
    float bn2v[2];
    int gnv[2];
    #pragma unroll
    for (int j = 0; j < 2; ++j) { gnv[j] = n0 + wc * 32 + j * 16 + lr; bn2v[j] = bn2[gnv[j]]; }
    #pragma unroll
    for (int i = 0; i < 2; ++i) {
        #pragma unroll
        for (int r = 0; r < 4; ++r) {
            int gm = m0 + wr * 32 + i * 16 + lk * 4 + r;
            float a2 = an2[gm];
            float sc = escale[gm];
            float rs = 0.f;
            #pragma unroll
            for (int j = 0; j < 2; ++j) {
                float dv = fmaxf(a2 + bn2v[j] - 2.0f * acc[i][j][r], 0.0f);
                short hb = f2bf(__expf(dv * sc));
                Eout[(size_t)gm * NS + gnv[j]] = hb;
                if (WSE) rs += bf2f(hb);
            }
            if (WSE) {
                #pragma unroll
                for (int m = 1; m < 16; m <<= 1) rs += __shfl_xor(rs, m);
                if (lr == 0) se[wc][wr * 32 + i * 16 + lk * 4 + r] = rs;
            }
        }
    }
    if (WSE) {
        __syncthreads();
        if (t < 64)
            sumEp[(size_t)(m0 + t) * 32 + blockIdx.y] =
                se[0][t] + se[1][t] + se[2][t] + se[3][t];
    }
}

// ====== MFMA GEMM raw partials, 8 waves / 512 thr (for w = e @ fromT, K-split 8) ======
__global__ __launch_bounds__(512)
void gemm_bt8(const short* __restrict__ A, const short* __restrict__ B, int K,
              int kslab, int nt, float* __restrict__ C, int ldc, size_t cstride)
{
    __shared__ short As[2][64][LDSP];
    __shared__ short Bs[2][128][LDSP];
    int t = threadIdx.x;
    int m0 = blockIdx.x * 64;
    int n0 = blockIdx.y * 128;
    int kbase = blockIdx.z * kslab;
    float* Cp = C + (size_t)blockIdx.z * cstride;
    int wid = t >> 6, lane = t & 63;
    int wr = wid >> 2, wc = wid & 3;      // 2 x 4 waves
    int lr = lane & 15, lk = lane >> 4;

    int ar = t >> 3, ak = (t & 7) * 8;
    int br = t >> 2, bk = (t & 3) * 16;
    const short* Ag = A + (size_t)(m0 + ar) * K + kbase + ak;
    const short* Bg = B + (size_t)(n0 + br) * K + kbase + bk;

    f32x4 acc[2][2] = {};
    bf16x8 ra0 = *(const bf16x8*)Ag;
    bf16x8 rb0 = *(const bf16x8*)Bg;
    bf16x8 rb1 = *(const bf16x8*)(Bg + 8);
    int cur = 0;
    *(bf16x8*)&As[0][ar][ak]     = ra0;
    *(bf16x8*)&Bs[0][br][bk]     = rb0;
    *(bf16x8*)&Bs[0][br][bk + 8] = rb1;

    for (int it = 0; it < nt; ++it) {
        __syncthreads();
        if (it + 1 < nt) {
            int ko = (it + 1) * 64;
            ra0 = *(const bf16x8*)(Ag + ko);
            rb0 = *(const bf16x8*)(Bg + ko);
            rb1 = *(const bf16x8*)(Bg + ko + 8);
        }
        #pragma unroll
        for (int ks = 0; ks < 2; ++ks) {
            int k0 = ks * 32 + lk * 8;
            bf16x8 af[2], bfr[2];
            #pragma unroll
            for (int i = 0; i < 2; ++i)
                af[i] = *(const bf16x8*)&As[cur][wr * 32 + i * 16 + lr][k0];
            #pragma unroll
            for (int j = 0; j < 2; ++j)
                bfr[j] = *(const bf16x8*)&Bs[cur][wc * 32 + j * 16 + lr][k0];
            #pragma unroll
            for (int i = 0; i < 2; ++i)
                #pragma unroll
                for (int j = 0; j < 2; ++j)
                    acc[i][j] = __builtin_amdgcn_mfma_f32_16x16x32_bf16(
                        af[i], bfr[j], acc[i][j], 0, 0, 0);
        }
        if (it + 1 < nt) {
            cur ^= 1;
            *(bf16x8*)&As[cur][ar][ak]     = ra0;
            *(bf16x8*)&Bs[cur][br][bk]     = rb0;
            *(bf16x8*)&Bs[cur][br][bk + 8] = rb1;
        }
    }
    #pragma unroll
    for (int i = 0; i < 2; ++i) {
        #pragma unroll
        for (int r = 0; r < 4; ++r) {
            int gm = m0 + wr * 32 + i * 16 + lk * 4 + r;
            #pragma unroll
            for (int j = 0; j < 2; ++j) {
                int gn = n0 + wc * 32 + j * 16 + lr;
                Cp[(size_t)gm * ldc + gn] = acc[i][j][r];
            }
        }
    }
}

// === xt = (sum of 8 w-slabs)/sumE (or matched row) -> bf16 + norm + escale2 ===
__global__ __launch_bounds__(256)
void xt_fin(const float* __restrict__ wpart, const float* __restrict__ sumEp,
            const int* __restrict__ midx, const float* __restrict__ fromf,
            const float* __restrict__ fbar, const float* __restrict__ fms,
            short* __restrict__ xtb, float* __restrict__ xtn2,
            float* __restrict__ escale2)
{
    __shared__ float red[4];
    __shared__ float bc[1];
    int b = blockIdx.x;
    int t = threadIdx.x;
    int d = t * 2;
    int mi = midx[b];
    if (t == 0) {
        float s = 0.f;
        #pragma unroll
        for (int k = 0; k < 32; ++k) s += sumEp[(size_t)b * 32 + k];
        bc[0] = 1.0f / s;
    }
    float v0 = 0.f, v1 = 0.f;
    #pragma unroll
    for (int sl = 0; sl < 8; ++sl) {
        float2 p = *(const float2*)(wpart + (size_t)sl * (BB * DDIM) + (size_t)b * DDIM + d);
        v0 += p.x; v1 += p.y;
    }
    __syncthreads();
    float inv = bc[0];
    v0 *= inv; v1 *= inv;
    if (mi < NS) {
        v0 = fromf[(size_t)mi * DDIM + d];
        v1 = fromf[(size_t)mi * DDIM + d + 1];
    }
    xtb[(size_t)b * DDIM + d]     = f2bf(v0);
    xtb[(size_t)b * DDIM + d + 1] = f2bf(v1);
    float nt2 = block_sum(v0 * v0 + v1 * v1, red);
    float2 fb2 = *(const float2*)(fbar + d);
    float fd = block_sum(v0 * fb2.x + v1 * fb2.y, red);
    if (t == 0) {
        xtn2[b] = nt2;
        escale2[b] = -TEMP / (fms[0] + nt2 - 2.0f * fd);
    }
}

// =============== y_star from bf16 e2T: weighted one-hot average ===============
__global__ __launch_bounds__(256)
void ystar_fin(const short* __restrict__ e2T, const int* __restrict__ labels,
               float* __restrict__ out)
{
    __shared__ float cred[NCLS + 1][4];
    int b = blockIdx.x;
    int t = threadIdx.x;
    const short* row = e2T + (size_t)b * NS + t * 16;
    bf16x8 h0 = *(const bf16x8*)row;
    bf16x8 h1 = *(const bf16x8*)(row + 8);
    float accs[NCLS] = {};
    float te = 0.f;
    #pragma unroll
    for (int q = 0; q < 4; ++q) {
        int4 lb = *(const int4*)(labels + t * 16 + q * 4);
        int lbl[4] = {lb.x, lb.y, lb.z, lb.w};
        #pragma unroll
        for (int e = 0; e < 4; ++e) {
            int idx = q * 4 + e;
            float ev = bf2f(idx < 8 ? h0[idx] : h1[idx - 8]);
            te += ev;
            #pragma unroll
            for (int c = 0; c < NCLS; ++c) accs[c] += (lbl[e] == c) ? ev : 0.f;
        }
    }
    int wid = t >> 6, lane = t & 63;
    #pragma unroll
    for (int c = 0; c < NCLS + 1; ++c) {
        float sv = (c < NCLS) ? accs[c] : te;
        #pragma unroll
        for (int off = 32; off > 0; off >>= 1) sv += __shfl_down(sv, off);
        if (lane == 0) cred[c][wid] = sv;
    }
    __syncthreads();
    if (t < NCLS) {
        float num = cred[t][0] + cred[t][1] + cred[t][2] + cred[t][3];
        float den = cred[NCLS][0] + cred[NCLS][1] + cred[NCLS][2] + cred[NCLS][3];
        out[b * NCLS + t] = num / den;
    }
}

extern "C" void kernel_launch(void* const* d_in, const int* in_sizes, int n_in,
                              void* d_out, int out_size, void* d_ws, size_t ws_size,
                              hipStream_t stream) {
    const float* x     = (const float*)d_in[0];
    const float* star  = (const float*)d_in[1];
    const float* from  = (const float*)d_in[2];
    const int*   label = (const int*)d_in[3];
    float* out = (float*)d_out;

    float* F = (float*)d_ws;                     // ~40 MB of workspace
    float* wpart = F;                            // 8 x [512][512] f32 (8 MB; region reserved 16)
    short* Sb    = (short*)(F + 4194304);        // star bf16  [4096][512]
    short* FTb   = (short*)(F + 5242880);        // fromT bf16 [512][4096]
    short* Fb    = (short*)(F + 6291456);        // from bf16  [4096][512]
    short* Eb    = (short*)(F + 7340032);        // eT bf16    [512][4096]
    short* E2b   = (short*)(F + 8388608);        // e2T bf16   [512][4096]
    short* Xb    = (short*)(F + 9437184);        // x bf16     [512][512]
    short* XTb   = (short*)(F + 9568256);        // xt bf16    [512][512]
    float* sn2   = F + 9699328;                  // 4096
    float* fn2   = F + 9703424;                  // 4096
    float* xn2   = F + 9707520;                  // 512
    float* xtn2  = F + 9708032;                  // 512
    float* esc1  = F + 9708544;                  // 512
    float* esc2  = F + 9709056;                  // 512
    float* sbar  = F + 9709568;                  // 512
    float* fbar  = F + 9710080;                  // 512
    float* sms   = F + 9710592;                  // 16
    float* fms   = F + 9710608;                  // 16
    float* sumEp = F + 9710624;                  // [512][32]
    float* scol  = F + 9727008;                  // 4096
    float* xcol  = F + 9731104;                  // 512
    int*   midx  = (int*)(F + 9731616);          // 512
    float* spart = F + 9732128;                  // [128][512]
    float* fpart = F + 9797664;                  // [128][512]

    prep<<<2944, 256, 0, stream>>>(x, star, from, Xb, Sb, FTb, Fb,
                                   xn2, sn2, fn2, scol, xcol, midx, spart, fpart);
    finmeans<<<2, 256, 0, stream>>>(spart, fpart, sn2, fn2, sbar, fbar, sms, fms);
    aux<<<144, 256, 0, stream>>>(x, star, sbar, sms, xn2, esc1, scol, xcol, midx);
    // eT[b][n] = bf16(exp(esc1[b]*clamp(xn2+sn2-2 x.star,0))) + sumE partials
    gemm_exp<1><<<dim3(8, 32), 512, 0, stream>>>(Xb, Sb, xn2, sn2, esc1, Eb, sumEp);
    // wpart[z][b][d] = sum_{n in slab z} eT[b][n]*fromT[d][n]  (8 slabs of K=512)
    gemm_bt8<<<dim3(8, 4, 8), 512, 0, stream>>>(Eb, FTb, NS, 512, 8, wpart, DDIM,
                                                (size_t)BB * DDIM);
    xt_fin<<<BB, 256, 0, stream>>>(wpart, sumEp, midx, from, fbar, fms,
                                   XTb, xtn2, esc2);
    // e2T[b][n] = bf16(exp(esc2[b]*clamp(xtn2+fn2-2 xt.from,0)))
    gemm_exp<0><<<dim3(8, 32), 512, 0, stream>>>(XTb, Fb, xtn2, fn2, esc2, E2b, nullptr);
    ystar_fin<<<BB, 256, 0, stream>>>(E2b, label, out);
}